// Round 7
// baseline (578.159 us; speedup 1.0000x reference)
//
#include <hip/hip_runtime.h>
#include <math.h>

#define NN_NODES 4096
#define D_IN 128
#define D_H 256
#define KTOP 17
#define NEDGE (NN_NODES * KTOP)
#define INV_TEMP 5.0f
#define EPSV 1e-8f

typedef __bf16 bf16x8 __attribute__((ext_vector_type(8)));
typedef float f32x4 __attribute__((ext_vector_type(4)));

// ---------------- helpers ----------------
__device__ __forceinline__ float block_reduce_sum(float v, float* sb) {
#pragma unroll
    for (int o = 32; o > 0; o >>= 1) v += __shfl_down(v, o, 64);
    int wid = threadIdx.x >> 6;
    __syncthreads();
    if ((threadIdx.x & 63) == 0) sb[wid] = v;
    __syncthreads();
    return sb[0] + sb[1] + sb[2] + sb[3];
}

__device__ __forceinline__ float block_reduce_max(float v, float* sb) {
#pragma unroll
    for (int o = 32; o > 0; o >>= 1) v = fmaxf(v, __shfl_down(v, o, 64));
    int wid = threadIdx.x >> 6;
    __syncthreads();
    if ((threadIdx.x & 63) == 0) sb[wid] = v;
    __syncthreads();
    return fmaxf(fmaxf(sb[0], sb[1]), fmaxf(sb[2], sb[3]));
}

// split fp32 into bf16 hi + bf16 lo (RNE both)
__device__ __forceinline__ void f2hilo(float x, unsigned short* h, unsigned short* l) {
    unsigned u = __float_as_uint(x);
    unsigned r = u + 0x7fff + ((u >> 16) & 1);
    unsigned short hh = (unsigned short)(r >> 16);
    float hf = __uint_as_float((unsigned)hh << 16);
    float lo = x - hf;
    unsigned ul = __float_as_uint(lo);
    unsigned rl = ul + 0x7fff + ((ul >> 16) & 1);
    *h = hh;
    *l = (unsigned short)(rl >> 16);
}

// ---------------- elementwise / setup ----------------
__global__ __launch_bounds__(256) void zero_f(float* p, int n) {
    int i = blockIdx.x * 256 + threadIdx.x;
    if (i < n) p[i] = 0.f;
}

__global__ __launch_bounds__(256) void zero_i(int* p, int n) {
    int i = blockIdx.x * 256 + threadIdx.x;
    if (i < n) p[i] = 0;
}

__global__ __launch_bounds__(256) void x1_kernel(const float* __restrict__ x,
                                                 const float* __restrict__ p_feat,
                                                 const float* __restrict__ p_shared,
                                                 float* __restrict__ x1) {
    int i = blockIdx.x * 256 + threadIdx.x;
    if (i >= NN_NODES * D_IN) return;
    int c = i & (D_IN - 1);
    float v = x[i] * p_feat[c];
    v = fmaxf(v, 0.0f) * p_shared[c];
    x1[i] = v;
}

__global__ __launch_bounds__(256) void deg_init(float* deg) {
    int i = blockIdx.x * 256 + threadIdx.x;
    if (i < NN_NODES) deg[i] = 1.0f;  // self loop
}

__global__ __launch_bounds__(256) void deg_edges(float* deg, const int* __restrict__ dst, int E) {
    for (int e = blockIdx.x * 256 + threadIdx.x; e < E; e += gridDim.x * 256)
        atomicAdd(&deg[dst[e]], 1.0f);
}

__global__ __launch_bounds__(256) void to_dinv(float* deg) {
    int i = blockIdx.x * 256 + threadIdx.x;
    if (i < NN_NODES) deg[i] = rsqrtf(deg[i]);
}

// ---------------- input-graph CSR (keyed by dst) ----------------
__global__ __launch_bounds__(256) void ecount_kernel(const int* __restrict__ dst, int* __restrict__ cnt, int E) {
    int e = blockIdx.x * 256 + threadIdx.x;
    if (e < E) atomicAdd(&cnt[dst[e]], 1);
}

__global__ __launch_bounds__(256) void efill_kernel(const int* __restrict__ src, const int* __restrict__ dst,
                                                    const int* __restrict__ ptr, int* __restrict__ cnt,
                                                    int* __restrict__ esrt, int E) {
    int e = blockIdx.x * 256 + threadIdx.x;
    if (e >= E) return;
    int d = dst[e];
    int p = ptr[d] + atomicAdd(&cnt[d], 1);
    esrt[p] = src[e];
}

// out[n][c] = act( dinv[n]^2*h[n][c] + sum_{edges s->n} dinv[s]*dinv[n]*h[s][c] + bias[c] )
__global__ void prop_gather(float* __restrict__ out, const float* __restrict__ h,
                            const float* __restrict__ dinv, const int* __restrict__ eptr,
                            const int* __restrict__ esrt, const float* __restrict__ bias,
                            int C, int act) {
    int n = blockIdx.x, t = threadIdx.x;
    float dn = dinv[n];
    float acc = dn * dn * h[(size_t)n * C + t];
    int p1 = eptr[n + 1];
    for (int p = eptr[n]; p < p1; ++p) {
        int s = esrt[p];
        acc += dinv[s] * dn * h[(size_t)s * C + t];
    }
    if (bias) acc += bias[t];
    if (act == 1) acc = fmaxf(acc, 0.f);
    else if (act == 2) acc = acc > 0.f ? acc : expm1f(acc);
    out[(size_t)n * C + t] = acc;
}

// h = concat(x1, agg)*p_balance; hn = h/(||h||+eps) -> bf16 hi/lo. block/row.
__global__ __launch_bounds__(256) void h_hn_kernel(const float* __restrict__ x1,
                                                   const float* __restrict__ agg,
                                                   const float* __restrict__ p_balance,
                                                   unsigned short* __restrict__ hn_hi,
                                                   unsigned short* __restrict__ hn_lo) {
    __shared__ float sb[4];
    int n = blockIdx.x, t = threadIdx.x;
    float v;
    if (t < D_IN) v = x1[(size_t)n * D_IN + t] * p_balance[t];
    else v = agg[(size_t)n * D_IN + (t - D_IN)] * p_balance[t];
    float ss = block_reduce_sum(v * v, sb);
    float inv = 1.0f / (sqrtf(ss) + EPSV);
    unsigned short h, l;
    f2hilo(v * inv, &h, &l);
    hn_hi[(size_t)n * D_H + t] = h;
    hn_lo[(size_t)n * D_H + t] = l;
}

// row normalize Z (C=256) -> bf16 hi/lo (Z unchanged)
__global__ __launch_bounds__(256) void rownorm_kernel(const float* __restrict__ Z,
                                                      unsigned short* __restrict__ zhi,
                                                      unsigned short* __restrict__ zlo) {
    __shared__ float sb[4];
    int n = blockIdx.x, t = threadIdx.x;
    float v = Z[(size_t)n * D_H + t];
    float ss = block_reduce_sum(v * v, sb);
    float inv = 1.0f / (sqrtf(ss) + EPSV);
    unsigned short h, l;
    f2hilo(v * inv, &h, &l);
    zhi[(size_t)n * D_H + t] = h;
    zlo[(size_t)n * D_H + t] = l;
}

// ---------------- fp32 GEMM (small NN cases) ----------------
#define BM 64
#define BN 64
#define BK 16

__global__ __launch_bounds__(256) void gemm_nn_kernel(const float* __restrict__ A,
                                                      const float* __restrict__ B,
                                                      float* __restrict__ C, int M, int Nn,
                                                      int Kk, const float* __restrict__ bias,
                                                      int ep) {
    __shared__ float As[BK][BM + 4];
    __shared__ float Bs[BK][BN + 4];
    const int tid = threadIdx.x;
    const int tx = tid & 15, ty = tid >> 4;
    const int m0 = blockIdx.y * BM, n0 = blockIdx.x * BN;
    const int arow = tid >> 2, acol = (tid & 3) << 2;
    const int brow = tid >> 4, bcol = (tid & 15) << 2;
    float acc[4][4] = {{0.f}};

    for (int k0 = 0; k0 < Kk; k0 += BK) {
        float4 av = *(const float4*)&A[(size_t)(m0 + arow) * Kk + k0 + acol];
        float4 bv = *(const float4*)&B[(size_t)(k0 + brow) * Nn + n0 + bcol];
        As[acol + 0][arow] = av.x;
        As[acol + 1][arow] = av.y;
        As[acol + 2][arow] = av.z;
        As[acol + 3][arow] = av.w;
        *(float4*)&Bs[brow][bcol] = bv;
        __syncthreads();
#pragma unroll
        for (int k = 0; k < BK; ++k) {
            float4 a = *(const float4*)&As[k][ty << 2];
            float4 b = *(const float4*)&Bs[k][tx << 2];
            acc[0][0] += a.x * b.x; acc[0][1] += a.x * b.y; acc[0][2] += a.x * b.z; acc[0][3] += a.x * b.w;
            acc[1][0] += a.y * b.x; acc[1][1] += a.y * b.y; acc[1][2] += a.y * b.z; acc[1][3] += a.y * b.w;
            acc[2][0] += a.z * b.x; acc[2][1] += a.z * b.y; acc[2][2] += a.z * b.z; acc[2][3] += a.z * b.w;
            acc[3][0] += a.w * b.x; acc[3][1] += a.w * b.y; acc[3][2] += a.w * b.z; acc[3][3] += a.w * b.w;
        }
        __syncthreads();
    }
    float bb[4] = {0.f, 0.f, 0.f, 0.f};
    if (ep) {
#pragma unroll
        for (int j = 0; j < 4; ++j) bb[j] = bias[n0 + (tx << 2) + j];
    }
#pragma unroll
    for (int i = 0; i < 4; ++i) {
        int m = m0 + (ty << 2) + i;
        float r[4];
#pragma unroll
        for (int j = 0; j < 4; ++j) {
            float v = acc[i][j] + bb[j];
            if (ep == 1) v = fmaxf(v, 0.0f);
            else if (ep == 2) v = v > 0.0f ? v : expm1f(v);
            r[j] = v;
        }
        *(float4*)&C[(size_t)m * Nn + n0 + (tx << 2)] = *(float4*)r;
    }
}

// ---------------- MFMA NT GEMM: C[4096,4096] = X @ Y^T, K=256, split-bf16 ----------------
__global__ __launch_bounds__(256) void gemm_nt_mfma(const unsigned short* __restrict__ Ahi,
                                                    const unsigned short* __restrict__ Alo,
                                                    const unsigned short* __restrict__ Bhi,
                                                    const unsigned short* __restrict__ Blo,
                                                    float* __restrict__ C) {
    __shared__ unsigned short lds[4 * 16 * 512];  // 64 KB
    const int tid = threadIdx.x;
    const int w = tid >> 6, lane = tid & 63;
    const int m0 = blockIdx.y * 128, n0 = blockIdx.x * 128;
    const int wmt = (w >> 1) * 4;
    const int wnt = (w & 1) * 4;

    f32x4 acc[4][4];
#pragma unroll
    for (int i = 0; i < 4; ++i)
#pragma unroll
        for (int j = 0; j < 4; ++j) acc[i][j] = (f32x4)(0.f);

    unsigned short* Ah = lds;
    unsigned short* Al = lds + 8192;
    unsigned short* Bh = lds + 16384;
    unsigned short* Bl = lds + 24576;

    const unsigned short* srcs[4] = {Ahi, Alo, Bhi, Blo};
    unsigned short* dsts[4] = {Ah, Al, Bh, Bl};

    const int lrow = lane & 15, lquad = lane >> 4;

    for (int k0 = 0; k0 < 256; k0 += 64) {
#pragma unroll
        for (int arr = 0; arr < 4; ++arr) {
            const unsigned short* src = srcs[arr];
            unsigned short* dst = dsts[arr];
            const int base0 = (arr < 2) ? m0 : n0;
#pragma unroll
            for (int ti = 0; ti < 4; ++ti) {
                int t = w + ti * 4;
                int row = base0 + (t & 7) * 16 + lrow;
                int kk = k0 + (t >> 3) * 32 + lquad * 8;
                uint4 v = *(const uint4*)&src[(size_t)row * 256 + kk];
                *(uint4*)&dst[t * 512 + lane * 8] = v;
            }
        }
        __syncthreads();
#pragma unroll
        for (int ksub = 0; ksub < 2; ++ksub) {
            bf16x8 ah[4], al[4], bh[4], bl[4];
#pragma unroll
            for (int i = 0; i < 4; ++i) {
                ah[i] = __builtin_bit_cast(bf16x8, *(const uint4*)&Ah[(ksub * 8 + wmt + i) * 512 + lane * 8]);
                al[i] = __builtin_bit_cast(bf16x8, *(const uint4*)&Al[(ksub * 8 + wmt + i) * 512 + lane * 8]);
                bh[i] = __builtin_bit_cast(bf16x8, *(const uint4*)&Bh[(ksub * 8 + wnt + i) * 512 + lane * 8]);
                bl[i] = __builtin_bit_cast(bf16x8, *(const uint4*)&Bl[(ksub * 8 + wnt + i) * 512 + lane * 8]);
            }
#pragma unroll
            for (int i = 0; i < 4; ++i)
#pragma unroll
                for (int j = 0; j < 4; ++j) {
                    acc[i][j] = __builtin_amdgcn_mfma_f32_16x16x32_bf16(ah[i], bh[j], acc[i][j], 0, 0, 0);
                    acc[i][j] = __builtin_amdgcn_mfma_f32_16x16x32_bf16(ah[i], bl[j], acc[i][j], 0, 0, 0);
                    acc[i][j] = __builtin_amdgcn_mfma_f32_16x16x32_bf16(al[i], bh[j], acc[i][j], 0, 0, 0);
                }
        }
        __syncthreads();
    }
    const int col = lane & 15, rq = (lane >> 4) * 4;
#pragma unroll
    for (int i = 0; i < 4; ++i) {
        int rb = m0 + (wmt + i) * 16 + rq;
#pragma unroll
        for (int j = 0; j < 4; ++j) {
            int cb = n0 + (wnt + j) * 16 + col;
#pragma unroll
            for (int r = 0; r < 4; ++r)
                C[(size_t)(rb + r) * NN_NODES + cb] = acc[i][j][r];
        }
    }
}

// ---------------- top-k: wave-local extraction + single merge ----------------
// 4 waves x 1024 disjoint elements. Per lane a cached best-of-16; per round a
// 6-step shfl_xor butterfly; only the unique owning lane rescans. No block
// barriers until the final 68-candidate merge on wave 0. Tie-break matches
// JAX top_k (value desc, index asc); output list order is irrelevant downstream.
__global__ __launch_bounds__(256) void topk_kernel(const float* __restrict__ S,
                                                   float* __restrict__ vals,
                                                   int* __restrict__ idxo) {
    __shared__ float cv[4 * KTOP];
    __shared__ int ci[4 * KTOP];
    const int i = blockIdx.x, t = threadIdx.x;
    const int lane = t & 63, w = t >> 6;
    const float* row = &S[(size_t)i * NN_NODES];
    float v[16];
    int id[16];
#pragma unroll
    for (int p = 0; p < 4; ++p) {
        int base = w * 1024 + p * 256 + lane * 4;
        float4 f = *(const float4*)&row[base];
        v[p * 4 + 0] = f.x; id[p * 4 + 0] = base + 0;
        v[p * 4 + 1] = f.y; id[p * 4 + 1] = base + 1;
        v[p * 4 + 2] = f.z; id[p * 4 + 2] = base + 2;
        v[p * 4 + 3] = f.w; id[p * 4 + 3] = base + 3;
    }
    float bv = v[0];
    int bi = id[0];
#pragma unroll
    for (int u = 1; u < 16; ++u)
        if (v[u] > bv || (v[u] == bv && id[u] < bi)) { bv = v[u]; bi = id[u]; }

    for (int k = 0; k < KTOP; ++k) {
        float mv = bv;
        int mi = bi;
#pragma unroll
        for (int o = 1; o < 64; o <<= 1) {
            float ov = __shfl_xor(mv, o, 64);
            int oi = __shfl_xor(mi, o, 64);
            if (ov > mv || (ov == mv && oi < mi)) { mv = ov; mi = oi; }
        }
        if (lane == 0) { cv[w * KTOP + k] = mv; ci[w * KTOP + k] = mi; }
        if (bi == mi) {  // unique owner (indices disjoint across lanes)
#pragma unroll
            for (int u = 0; u < 16; ++u)
                if (id[u] == mi) v[u] = -INFINITY;
            bv = v[0]; bi = id[0];
#pragma unroll
            for (int u = 1; u < 16; ++u)
                if (v[u] > bv || (v[u] == bv && id[u] < bi)) { bv = v[u]; bi = id[u]; }
        }
    }
    __syncthreads();
    if (w == 0) {
        float a = cv[lane];
        int ai = ci[lane];
        float b = -INFINITY;
        int bj = 0x7fffffff;
        if (lane < 4) { b = cv[64 + lane]; bj = ci[64 + lane]; }
        for (int k = 0; k < KTOP; ++k) {
            float mv = a; int mi = ai;
            if (b > mv || (b == mv && bj < mi)) { mv = b; mi = bj; }
#pragma unroll
            for (int o = 1; o < 64; o <<= 1) {
                float ov = __shfl_xor(mv, o, 64);
                int oi = __shfl_xor(mi, o, 64);
                if (ov > mv || (ov == mv && oi < mi)) { mv = ov; mi = oi; }
            }
            if (lane == 0) {
                vals[i * KTOP + k] = isnan(mv) ? 0.f : mv;
                idxo[i * KTOP + k] = mi;
            }
            if (ai == mi) a = -INFINITY;
            if (bj == mi) b = -INFINITY;
        }
    }
}

// ---------------- sparse W construction ----------------
__global__ __launch_bounds__(256) void count_indeg(const int* __restrict__ idx, int* __restrict__ cnt) {
    int e = blockIdx.x * 256 + threadIdx.x;
    if (e < NEDGE) atomicAdd(&cnt[idx[e]], 1);
}

__global__ __launch_bounds__(256) void scan_kernel(const int* __restrict__ cnt, int* __restrict__ ptr) {
    __shared__ int tmp[256];
    int t = threadIdx.x;
    int base = t * 16;
    int local[16]; int s = 0;
#pragma unroll
    for (int u = 0; u < 16; ++u) { local[u] = s; s += cnt[base + u]; }
    tmp[t] = s;
    __syncthreads();
    for (int off = 1; off < 256; off <<= 1) {
        int v = (t >= off) ? tmp[t - off] : 0;
        __syncthreads();
        tmp[t] += v;
        __syncthreads();
    }
    int prefix = (t > 0) ? tmp[t - 1] : 0;
#pragma unroll
    for (int u = 0; u < 16; ++u) ptr[base + u] = prefix + local[u];
    if (t == 255) ptr[NN_NODES] = prefix + s;
}

__global__ __launch_bounds__(256) void fill_rev(const int* __restrict__ idx, const float* __restrict__ vals,
                                                const int* __restrict__ ptr, int* __restrict__ fcnt,
                                                int* __restrict__ rrow, int* __restrict__ rsrc,
                                                float* __restrict__ rval) {
    int e = blockIdx.x * 256 + threadIdx.x;
    if (e >= NEDGE) return;
    int i = e / KTOP;
    int j = idx[e];
    int p = ptr[j] + atomicAdd(&fcnt[j], 1);
    rrow[p] = j; rsrc[p] = i; rval[p] = vals[e];
}

__global__ __launch_bounds__(256) void wfwd_kernel(const int* __restrict__ idx, const float* __restrict__ vals,
                                                   float* __restrict__ wfwd) {
    int e = blockIdx.x * 256 + threadIdx.x;
    if (e >= NEDGE) return;
    int i = e / KTOP;
    int j = idx[e];
    float a = vals[e];
    float c = 1.0f;
    const int* lj = &idx[j * KTOP];
#pragma unroll
    for (int k = 0; k < KTOP; ++k)
        if (lj[k] == i) { a += vals[j * KTOP + k]; c = 2.0f; }
    float w = a / c;
    wfwd[e] = w > 0.f ? w : 0.f;
}

__global__ __launch_bounds__(256) void wrev_kernel(const int* __restrict__ idx,
                                                   const int* __restrict__ rrow, const int* __restrict__ rsrc,
                                                   const float* __restrict__ rval, float* __restrict__ wrev) {
    int e = blockIdx.x * 256 + threadIdx.x;
    if (e >= NEDGE) return;
    int i = rrow[e], s = rsrc[e];
    const int* li = &idx[i * KTOP];
    bool dup = false;
#pragma unroll
    for (int k = 0; k < KTOP; ++k)
        if (li[k] == s) dup = true;
    float w = dup ? 0.f : fmaxf(rval[e], 0.f);
    wrev[e] = w;
}

// out[i,:] = act(sum_j W[i,j]*X[j,:] + bias)
__global__ __launch_bounds__(256) void spmm_kernel(float* __restrict__ out, const float* __restrict__ X,
                                                   const int* __restrict__ idx, const float* __restrict__ wfwd,
                                                   const int* __restrict__ ptr, const int* __restrict__ rsrc,
                                                   const float* __restrict__ wrev,
                                                   const float* __restrict__ bias, int act) {
    int i = blockIdx.x, c = threadIdx.x;
    float acc = 0.f;
#pragma unroll
    for (int k = 0; k < KTOP; ++k) {
        int j = idx[i * KTOP + k];
        float w = wfwd[i * KTOP + k];
        acc += w * X[(size_t)j * D_H + c];
    }
    int p1 = ptr[i + 1];
    for (int p = ptr[i]; p < p1; ++p) {
        float w = wrev[p];
        if (w != 0.f) acc += w * X[(size_t)rsrc[p] * D_H + c];
    }
    acc += bias[c];
    if (act == 1) acc = fmaxf(acc, 0.f);
    else acc = acc > 0.f ? acc : expm1f(acc);
    out[(size_t)i * D_H + c] = acc;
}

// ---------------- softmax stats (block per row) ----------------
__global__ __launch_bounds__(256) void softmax_stats(const float* __restrict__ S,
                                                     float* __restrict__ mrow,
                                                     float* __restrict__ zrow,
                                                     float* __restrict__ diag) {
    __shared__ float sb[4];
    int i = blockIdx.x, t = threadIdx.x;
    const float* r = &S[(size_t)i * NN_NODES];
    float m = -INFINITY;
    for (int j = t; j < NN_NODES; j += 256) m = fmaxf(m, r[j] * INV_TEMP);
    m = block_reduce_max(m, sb);
    __syncthreads();
    float z = 0.f;
    for (int j = t; j < NN_NODES; j += 256) z += expf(r[j] * INV_TEMP - m);
    z = block_reduce_sum(z, sb);
    if (t == 0) {
        mrow[i] = m;
        zrow[i] = z;
        diag[i] = expf(r[i] * INV_TEMP - m) / z;
    }
}

// pf/pb edge-parallel (W symmetric)
__global__ __launch_bounds__(256) void pfpb_edges(const float* __restrict__ S,
                                                  const int* __restrict__ rows_arr,
                                                  const int* __restrict__ cols,
                                                  const float* __restrict__ w,
                                                  const float* __restrict__ mrow,
                                                  const float* __restrict__ zrow,
                                                  float* __restrict__ pf, float* __restrict__ pb,
                                                  int fwd) {
    int e = blockIdx.x * 256 + threadIdx.x;
    if (e >= NEDGE) return;
    int i, j;
    if (fwd) { i = e / KTOP; j = cols[e]; }
    else { i = rows_arr[e]; j = cols[e]; }
    float wv = w[e];
    if (wv == 0.f) return;
    float sf = S[(size_t)i * NN_NODES + j];
    float sbk = S[(size_t)j * NN_NODES + i];
    float pfv = expf(sf * INV_TEMP - mrow[i]) / zrow[i] * wv;
    float pbv = expf(sbk * INV_TEMP - mrow[j]) / zrow[j] * wv;
    atomicAdd(&pf[i], pfv);
    atomicAdd(&pb[i], pbv);
}

__global__ __launch_bounds__(256) void loss_kernel(const float* __restrict__ diag,
                                                   const float* __restrict__ pf,
                                                   const float* __restrict__ pb,
                                                   float* __restrict__ out) {
    __shared__ float sb[4];
    int t = threadIdx.x;
    float s = 0.f;
    for (int i = t; i < NN_NODES; i += 256) {
        s += -logf(fmaxf(diag[i], EPSV));
        s += 0.5f * (-logf(fmaxf(pf[i], EPSV)) - logf(fmaxf(pb[i], EPSV)));
    }
    float tot = block_reduce_sum(s, sb);
    if (t == 0) out[0] = tot / (float)NN_NODES;
}

// ---------------- launch ----------------
extern "C" void kernel_launch(void* const* d_in, const int* in_sizes, int n_in,
                              void* d_out, int out_size, void* d_ws, size_t ws_size,
                              hipStream_t stream) {
    (void)n_in; (void)out_size; (void)ws_size;
    const float* x = (const float*)d_in[0];
    const int* esrc = (const int*)d_in[1];
    const int* edst = (const int*)d_in[2];
    const float* p_feat = (const float*)d_in[3];
    const float* p_shared = (const float*)d_in[4];
    const float* p_balance = (const float*)d_in[5];
    const float* W1 = (const float*)d_in[6];
    const float* b1 = (const float*)d_in[7];
    const float* W2 = (const float*)d_in[8];
    const float* b2 = (const float*)d_in[9];
    const int E = in_sizes[1];

    float* ws = (float*)d_ws;
    size_t off = 0;
    float* SIM = ws + off; off += (size_t)NN_NODES * NN_NODES;
    float* X1  = ws + off; off += (size_t)NN_NODES * D_IN;
    float* AGG = ws + off; off += (size_t)NN_NODES * D_IN;
    float* T1  = ws + off; off += (size_t)NN_NODES * D_H;
    float* H1  = ws + off; off += (size_t)NN_NODES * D_H;
    float* T2  = ws + off; off += (size_t)NN_NODES * D_H;
    float* Z1  = ws + off; off += (size_t)NN_NODES * D_H;
    float* G1  = ws + off; off += (size_t)NN_NODES * D_H;
    float* Z2  = ws + off; off += (size_t)NN_NODES * D_H;
    float* DINV = ws + off; off += NN_NODES;
    float* VALS = ws + off; off += (size_t)NEDGE;
    int*   IDX  = (int*)(ws + off); off += (size_t)NEDGE;
    float* WFWD = ws + off; off += (size_t)NEDGE;
    int*   RPTR = (int*)(ws + off); off += NN_NODES + 1;
    int*   FCNT = (int*)(ws + off); off += NN_NODES;
    int*   RROW = (int*)(ws + off); off += (size_t)NEDGE;
    int*   RSRC = (int*)(ws + off); off += (size_t)NEDGE;
    float* RVAL = ws + off; off += (size_t)NEDGE;
    float* WREV = ws + off; off += (size_t)NEDGE;
    float* MROW = ws + off; off += NN_NODES;
    float* ZROW = ws + off; off += NN_NODES;
    float* DIAG = ws + off; off += NN_NODES;
    float* PF = ws + off; off += NN_NODES;
    float* PB = ws + off; off += NN_NODES;
    unsigned short* HNhi = (unsigned short*)(ws + off); off += (size_t)NN_NODES * D_H / 2;
    unsigned short* HNlo = (unsigned short*)(ws + off); off += (size_t)NN_NODES * D_H / 2;
    unsigned short* Z1hi = (unsigned short*)(ws + off); off += (size_t)NN_NODES * D_H / 2;
    unsigned short* Z1lo = (unsigned short*)(ws + off); off += (size_t)NN_NODES * D_H / 2;
    unsigned short* Z2hi = (unsigned short*)(ws + off); off += (size_t)NN_NODES * D_H / 2;
    unsigned short* Z2lo = (unsigned short*)(ws + off); off += (size_t)NN_NODES * D_H / 2;
    int* ECNT = (int*)(ws + off); off += NN_NODES;
    int* EPTR = (int*)(ws + off); off += NN_NODES + 1;
    int* ESRT = (int*)(ws + off); off += (size_t)E;

    const int EB = (NEDGE + 255) / 256;
    const int NB = (NN_NODES + 255) / 256;
    const int EBi = (E + 255) / 256;

    // 1. x1
    x1_kernel<<<(NN_NODES * D_IN + 255) / 256, 256, 0, stream>>>(x, p_feat, p_shared, X1);
    // 2. degrees -> dinv, input-graph CSR
    deg_init<<<NB, 256, 0, stream>>>(DINV);
    deg_edges<<<512, 256, 0, stream>>>(DINV, edst, E);
    to_dinv<<<NB, 256, 0, stream>>>(DINV);
    zero_i<<<NB, 256, 0, stream>>>(ECNT, NN_NODES);
    ecount_kernel<<<EBi, 256, 0, stream>>>(edst, ECNT, E);
    scan_kernel<<<1, 256, 0, stream>>>(ECNT, EPTR);
    zero_i<<<NB, 256, 0, stream>>>(ECNT, NN_NODES);
    efill_kernel<<<EBi, 256, 0, stream>>>(esrc, edst, EPTR, ECNT, ESRT, E);
    // 3. agg = A_norm @ x1  (gather)
    prop_gather<<<NN_NODES, D_IN, 0, stream>>>(AGG, X1, DINV, EPTR, ESRT, nullptr, D_IN, 0);
    // 4. h, hn (bf16 hi/lo)
    h_hn_kernel<<<NN_NODES, 256, 0, stream>>>(X1, AGG, p_balance, HNhi, HNlo);
    // 5. sim = hn @ hn^T  (MFMA split-bf16)
    {
        dim3 g(NN_NODES / 128, NN_NODES / 128);
        gemm_nt_mfma<<<g, 256, 0, stream>>>(HNhi, HNlo, HNhi, HNlo, SIM);
    }
    // 6. topk
    topk_kernel<<<NN_NODES, 256, 0, stream>>>(SIM, VALS, IDX);
    // 7. sparse W: reverse CSR + edge weights
    zero_i<<<NB, 256, 0, stream>>>(FCNT, NN_NODES);
    count_indeg<<<EB, 256, 0, stream>>>(IDX, FCNT);
    scan_kernel<<<1, 256, 0, stream>>>(FCNT, RPTR);
    zero_i<<<NB, 256, 0, stream>>>(FCNT, NN_NODES);
    fill_rev<<<EB, 256, 0, stream>>>(IDX, VALS, RPTR, FCNT, RROW, RSRC, RVAL);
    wfwd_kernel<<<EB, 256, 0, stream>>>(IDX, VALS, WFWD);
    wrev_kernel<<<EB, 256, 0, stream>>>(IDX, RROW, RSRC, RVAL, WREV);
    // 8. t1 = x1 @ W1
    {
        dim3 g(D_H / BN, NN_NODES / BM);
        gemm_nn_kernel<<<g, 256, 0, stream>>>(X1, W1, T1, NN_NODES, D_H, D_IN, nullptr, 0);
    }
    // 9. h1 = relu(prop(t1) + b1)  (gather, fused bias+relu)
    prop_gather<<<NN_NODES, D_H, 0, stream>>>(H1, T1, DINV, EPTR, ESRT, b1, D_H, 1);
    // 10. z1 = elu(prop(h1@W2) + b2)
    {
        dim3 g(D_H / BN, NN_NODES / BM);
        gemm_nn_kernel<<<g, 256, 0, stream>>>(H1, W2, T2, NN_NODES, D_H, D_H, nullptr, 0);
    }
    prop_gather<<<NN_NODES, D_H, 0, stream>>>(Z1, T2, DINV, EPTR, ESRT, b2, D_H, 2);
    // 11. g1 = relu(W @ t1 + b1)   [sparse]
    spmm_kernel<<<NN_NODES, 256, 0, stream>>>(G1, T1, IDX, WFWD, RPTR, RSRC, WREV, b1, 1);
    // 12. g2 = g1 @ W2 (into T2)
    {
        dim3 g(D_H / BN, NN_NODES / BM);
        gemm_nn_kernel<<<g, 256, 0, stream>>>(G1, W2, T2, NN_NODES, D_H, D_H, nullptr, 0);
    }
    // 13. z2 = elu(W @ g2 + b2)   [sparse]
    spmm_kernel<<<NN_NODES, 256, 0, stream>>>(Z2, T2, IDX, WFWD, RPTR, RSRC, WREV, b2, 2);
    // 14. normalize z1, z2 -> bf16 hi/lo
    rownorm_kernel<<<NN_NODES, 256, 0, stream>>>(Z1, Z1hi, Z1lo);
    rownorm_kernel<<<NN_NODES, 256, 0, stream>>>(Z2, Z2hi, Z2lo);
    // 15. S = z1n @ z2n^T (MFMA split-bf16, reuse SIM)
    {
        dim3 g(NN_NODES / 128, NN_NODES / 128);
        gemm_nt_mfma<<<g, 256, 0, stream>>>(Z1hi, Z1lo, Z2hi, Z2lo, SIM);
    }
    // 16. softmax stats
    softmax_stats<<<NN_NODES, 256, 0, stream>>>(SIM, MROW, ZROW, DIAG);
    // 17. pf / pb (sparse, edge-parallel)
    zero_f<<<NB, 256, 0, stream>>>(PF, NN_NODES);
    zero_f<<<NB, 256, 0, stream>>>(PB, NN_NODES);
    pfpb_edges<<<EB, 256, 0, stream>>>(SIM, nullptr, IDX, WFWD, MROW, ZROW, PF, PB, 1);
    pfpb_edges<<<EB, 256, 0, stream>>>(SIM, RROW, RSRC, WREV, MROW, ZROW, PF, PB, 0);
    // 18. loss
    loss_kernel<<<1, 256, 0, stream>>>(DIAG, PF, PB, (float*)d_out);
}

// Round 8
// 561.176 us; speedup vs baseline: 1.0303x; 1.0303x over previous
//
#include <hip/hip_runtime.h>
#include <math.h>

#define NN_NODES 4096
#define D_IN 128
#define D_H 256
#define KTOP 17
#define NEDGE (NN_NODES * KTOP)
#define INV_TEMP 5.0f
#define EPSV 1e-8f

typedef __bf16 bf16x8 __attribute__((ext_vector_type(8)));
typedef float f32x4 __attribute__((ext_vector_type(4)));

// ---------------- helpers ----------------
__device__ __forceinline__ float block_reduce_sum(float v, float* sb) {
#pragma unroll
    for (int o = 32; o > 0; o >>= 1) v += __shfl_down(v, o, 64);
    int wid = threadIdx.x >> 6;
    __syncthreads();
    if ((threadIdx.x & 63) == 0) sb[wid] = v;
    __syncthreads();
    return sb[0] + sb[1] + sb[2] + sb[3];
}

// split fp32 into bf16 hi + bf16 lo (RNE both)
__device__ __forceinline__ void f2hilo(float x, unsigned short* h, unsigned short* l) {
    unsigned u = __float_as_uint(x);
    unsigned r = u + 0x7fff + ((u >> 16) & 1);
    unsigned short hh = (unsigned short)(r >> 16);
    float hf = __uint_as_float((unsigned)hh << 16);
    float lo = x - hf;
    unsigned ul = __float_as_uint(lo);
    unsigned rl = ul + 0x7fff + ((ul >> 16) & 1);
    *h = hh;
    *l = (unsigned short)(rl >> 16);
}

// ---------------- elementwise / setup ----------------
__global__ __launch_bounds__(256) void zero_f(float* p, int n) {
    int i = blockIdx.x * 256 + threadIdx.x;
    if (i < n) p[i] = 0.f;
}

__global__ __launch_bounds__(256) void zero_i(int* p, int n) {
    int i = blockIdx.x * 256 + threadIdx.x;
    if (i < n) p[i] = 0;
}

__global__ __launch_bounds__(256) void x1_kernel(const float* __restrict__ x,
                                                 const float* __restrict__ p_feat,
                                                 const float* __restrict__ p_shared,
                                                 float* __restrict__ x1) {
    int i = blockIdx.x * 256 + threadIdx.x;
    if (i >= NN_NODES * D_IN) return;
    int c = i & (D_IN - 1);
    float v = x[i] * p_feat[c];
    v = fmaxf(v, 0.0f) * p_shared[c];
    x1[i] = v;
}

__global__ __launch_bounds__(256) void deg_init(float* deg) {
    int i = blockIdx.x * 256 + threadIdx.x;
    if (i < NN_NODES) deg[i] = 1.0f;  // self loop
}

__global__ __launch_bounds__(256) void deg_edges(float* deg, const int* __restrict__ dst, int E) {
    for (int e = blockIdx.x * 256 + threadIdx.x; e < E; e += gridDim.x * 256)
        atomicAdd(&deg[dst[e]], 1.0f);
}

__global__ __launch_bounds__(256) void to_dinv(float* deg) {
    int i = blockIdx.x * 256 + threadIdx.x;
    if (i < NN_NODES) deg[i] = rsqrtf(deg[i]);
}

// ---------------- input-graph CSR (keyed by dst) ----------------
__global__ __launch_bounds__(256) void ecount_kernel(const int* __restrict__ dst, int* __restrict__ cnt, int E) {
    int e = blockIdx.x * 256 + threadIdx.x;
    if (e < E) atomicAdd(&cnt[dst[e]], 1);
}

__global__ __launch_bounds__(256) void efill_kernel(const int* __restrict__ src, const int* __restrict__ dst,
                                                    const int* __restrict__ ptr, int* __restrict__ cnt,
                                                    int* __restrict__ esrt, int E) {
    int e = blockIdx.x * 256 + threadIdx.x;
    if (e >= E) return;
    int d = dst[e];
    int p = ptr[d] + atomicAdd(&cnt[d], 1);
    esrt[p] = src[e];
}

// out[n][c] = act( dinv[n]^2*h[n][c] + sum_{edges s->n} dinv[s]*dinv[n]*h[s][c] + bias[c] )
__global__ void prop_gather(float* __restrict__ out, const float* __restrict__ h,
                            const float* __restrict__ dinv, const int* __restrict__ eptr,
                            const int* __restrict__ esrt, const float* __restrict__ bias,
                            int C, int act) {
    int n = blockIdx.x, t = threadIdx.x;
    float dn = dinv[n];
    float acc = dn * dn * h[(size_t)n * C + t];
    int p1 = eptr[n + 1];
    for (int p = eptr[n]; p < p1; ++p) {
        int s = esrt[p];
        acc += dinv[s] * dn * h[(size_t)s * C + t];
    }
    if (bias) acc += bias[t];
    if (act == 1) acc = fmaxf(acc, 0.f);
    else if (act == 2) acc = acc > 0.f ? acc : expm1f(acc);
    out[(size_t)n * C + t] = acc;
}

// h = concat(x1, agg)*p_balance; hn = h/(||h||+eps) -> bf16 hi/lo. block/row.
__global__ __launch_bounds__(256) void h_hn_kernel(const float* __restrict__ x1,
                                                   const float* __restrict__ agg,
                                                   const float* __restrict__ p_balance,
                                                   unsigned short* __restrict__ hn_hi,
                                                   unsigned short* __restrict__ hn_lo) {
    __shared__ float sb[4];
    int n = blockIdx.x, t = threadIdx.x;
    float v;
    if (t < D_IN) v = x1[(size_t)n * D_IN + t] * p_balance[t];
    else v = agg[(size_t)n * D_IN + (t - D_IN)] * p_balance[t];
    float ss = block_reduce_sum(v * v, sb);
    float inv = 1.0f / (sqrtf(ss) + EPSV);
    unsigned short h, l;
    f2hilo(v * inv, &h, &l);
    hn_hi[(size_t)n * D_H + t] = h;
    hn_lo[(size_t)n * D_H + t] = l;
}

// row normalize Z (C=256) -> bf16 hi/lo (Z unchanged)
__global__ __launch_bounds__(256) void rownorm_kernel(const float* __restrict__ Z,
                                                      unsigned short* __restrict__ zhi,
                                                      unsigned short* __restrict__ zlo) {
    __shared__ float sb[4];
    int n = blockIdx.x, t = threadIdx.x;
    float v = Z[(size_t)n * D_H + t];
    float ss = block_reduce_sum(v * v, sb);
    float inv = 1.0f / (sqrtf(ss) + EPSV);
    unsigned short h, l;
    f2hilo(v * inv, &h, &l);
    zhi[(size_t)n * D_H + t] = h;
    zlo[(size_t)n * D_H + t] = l;
}

// ---------------- fp32 GEMM (small NN cases) ----------------
#define BM 64
#define BN 64
#define BK 16

__global__ __launch_bounds__(256) void gemm_nn_kernel(const float* __restrict__ A,
                                                      const float* __restrict__ B,
                                                      float* __restrict__ C, int M, int Nn,
                                                      int Kk, const float* __restrict__ bias,
                                                      int ep) {
    __shared__ float As[BK][BM + 4];
    __shared__ float Bs[BK][BN + 4];
    const int tid = threadIdx.x;
    const int tx = tid & 15, ty = tid >> 4;
    const int m0 = blockIdx.y * BM, n0 = blockIdx.x * BN;
    const int arow = tid >> 2, acol = (tid & 3) << 2;
    const int brow = tid >> 4, bcol = (tid & 15) << 2;
    float acc[4][4] = {{0.f}};

    for (int k0 = 0; k0 < Kk; k0 += BK) {
        float4 av = *(const float4*)&A[(size_t)(m0 + arow) * Kk + k0 + acol];
        float4 bv = *(const float4*)&B[(size_t)(k0 + brow) * Nn + n0 + bcol];
        As[acol + 0][arow] = av.x;
        As[acol + 1][arow] = av.y;
        As[acol + 2][arow] = av.z;
        As[acol + 3][arow] = av.w;
        *(float4*)&Bs[brow][bcol] = bv;
        __syncthreads();
#pragma unroll
        for (int k = 0; k < BK; ++k) {
            float4 a = *(const float4*)&As[k][ty << 2];
            float4 b = *(const float4*)&Bs[k][tx << 2];
            acc[0][0] += a.x * b.x; acc[0][1] += a.x * b.y; acc[0][2] += a.x * b.z; acc[0][3] += a.x * b.w;
            acc[1][0] += a.y * b.x; acc[1][1] += a.y * b.y; acc[1][2] += a.y * b.z; acc[1][3] += a.y * b.w;
            acc[2][0] += a.z * b.x; acc[2][1] += a.z * b.y; acc[2][2] += a.z * b.z; acc[2][3] += a.z * b.w;
            acc[3][0] += a.w * b.x; acc[3][1] += a.w * b.y; acc[3][2] += a.w * b.z; acc[3][3] += a.w * b.w;
        }
        __syncthreads();
    }
    float bb[4] = {0.f, 0.f, 0.f, 0.f};
    if (ep) {
#pragma unroll
        for (int j = 0; j < 4; ++j) bb[j] = bias[n0 + (tx << 2) + j];
    }
#pragma unroll
    for (int i = 0; i < 4; ++i) {
        int m = m0 + (ty << 2) + i;
        float r[4];
#pragma unroll
        for (int j = 0; j < 4; ++j) {
            float v = acc[i][j] + bb[j];
            if (ep == 1) v = fmaxf(v, 0.0f);
            else if (ep == 2) v = v > 0.0f ? v : expm1f(v);
            r[j] = v;
        }
        *(float4*)&C[(size_t)m * Nn + n0 + (tx << 2)] = *(float4*)r;
    }
}

// ---------------- MFMA NT GEMM: C[4096,4096] = X @ Y^T, K=256, split-bf16 ----------------
// If zrow != nullptr, also accumulates row sums of exp(INV_TEMP * C) into zrow
// (fused softmax denominator; S in [-1,1] so no max-subtraction needed).
__global__ __launch_bounds__(256) void gemm_nt_mfma(const unsigned short* __restrict__ Ahi,
                                                    const unsigned short* __restrict__ Alo,
                                                    const unsigned short* __restrict__ Bhi,
                                                    const unsigned short* __restrict__ Blo,
                                                    float* __restrict__ C,
                                                    float* __restrict__ zrow) {
    __shared__ unsigned short lds[4 * 16 * 512];  // 64 KB
    const int tid = threadIdx.x;
    const int w = tid >> 6, lane = tid & 63;
    const int m0 = blockIdx.y * 128, n0 = blockIdx.x * 128;
    const int wmt = (w >> 1) * 4;
    const int wnt = (w & 1) * 4;

    f32x4 acc[4][4];
#pragma unroll
    for (int i = 0; i < 4; ++i)
#pragma unroll
        for (int j = 0; j < 4; ++j) acc[i][j] = (f32x4)(0.f);

    unsigned short* Ah = lds;
    unsigned short* Al = lds + 8192;
    unsigned short* Bh = lds + 16384;
    unsigned short* Bl = lds + 24576;

    const unsigned short* srcs[4] = {Ahi, Alo, Bhi, Blo};
    unsigned short* dsts[4] = {Ah, Al, Bh, Bl};

    const int lrow = lane & 15, lquad = lane >> 4;

    for (int k0 = 0; k0 < 256; k0 += 64) {
#pragma unroll
        for (int arr = 0; arr < 4; ++arr) {
            const unsigned short* src = srcs[arr];
            unsigned short* dst = dsts[arr];
            const int base0 = (arr < 2) ? m0 : n0;
#pragma unroll
            for (int ti = 0; ti < 4; ++ti) {
                int t = w + ti * 4;
                int row = base0 + (t & 7) * 16 + lrow;
                int kk = k0 + (t >> 3) * 32 + lquad * 8;
                uint4 v = *(const uint4*)&src[(size_t)row * 256 + kk];
                *(uint4*)&dst[t * 512 + lane * 8] = v;
            }
        }
        __syncthreads();
#pragma unroll
        for (int ksub = 0; ksub < 2; ++ksub) {
            bf16x8 ah[4], al[4], bh[4], bl[4];
#pragma unroll
            for (int i = 0; i < 4; ++i) {
                ah[i] = __builtin_bit_cast(bf16x8, *(const uint4*)&Ah[(ksub * 8 + wmt + i) * 512 + lane * 8]);
                al[i] = __builtin_bit_cast(bf16x8, *(const uint4*)&Al[(ksub * 8 + wmt + i) * 512 + lane * 8]);
                bh[i] = __builtin_bit_cast(bf16x8, *(const uint4*)&Bh[(ksub * 8 + wnt + i) * 512 + lane * 8]);
                bl[i] = __builtin_bit_cast(bf16x8, *(const uint4*)&Bl[(ksub * 8 + wnt + i) * 512 + lane * 8]);
            }
#pragma unroll
            for (int i = 0; i < 4; ++i)
#pragma unroll
                for (int j = 0; j < 4; ++j) {
                    acc[i][j] = __builtin_amdgcn_mfma_f32_16x16x32_bf16(ah[i], bh[j], acc[i][j], 0, 0, 0);
                    acc[i][j] = __builtin_amdgcn_mfma_f32_16x16x32_bf16(ah[i], bl[j], acc[i][j], 0, 0, 0);
                    acc[i][j] = __builtin_amdgcn_mfma_f32_16x16x32_bf16(al[i], bh[j], acc[i][j], 0, 0, 0);
                }
        }
        __syncthreads();
    }
    const int col = lane & 15, rq = (lane >> 4) * 4;
#pragma unroll
    for (int i = 0; i < 4; ++i) {
        int rb = m0 + (wmt + i) * 16 + rq;
#pragma unroll
        for (int j = 0; j < 4; ++j) {
            int cb = n0 + (wnt + j) * 16 + col;
#pragma unroll
            for (int r = 0; r < 4; ++r)
                C[(size_t)(rb + r) * NN_NODES + cb] = acc[i][j][r];
        }
    }
    if (zrow) {
#pragma unroll
        for (int i = 0; i < 4; ++i) {
            int rb = m0 + (wmt + i) * 16 + rq;
#pragma unroll
            for (int r = 0; r < 4; ++r) {
                float s = 0.f;
#pragma unroll
                for (int j = 0; j < 4; ++j) s += __expf(INV_TEMP * acc[i][j][r]);
#pragma unroll
                for (int o = 1; o < 16; o <<= 1) s += __shfl_xor(s, o, 64);
                if ((lane & 15) == 0) atomicAdd(&zrow[rb + r], s);
            }
        }
    }
}

// ---------------- top-k (block per row, register-resident; round-6 version) ----------------
__global__ __launch_bounds__(256) void topk_kernel(const float* __restrict__ S,
                                                   float* __restrict__ vals,
                                                   int* __restrict__ idxo) {
    __shared__ float wvs[4];
    __shared__ int wis[4];
    const int i = blockIdx.x, t = threadIdx.x;
    const int lane = t & 63, wid = t >> 6;
    const float* row = &S[(size_t)i * NN_NODES];
    float v[16];
    int id[16];
#pragma unroll
    for (int u = 0; u < 4; ++u) {
        int base = u * 1024 + t * 4;
        float4 f = *(const float4*)&row[base];
        v[u * 4 + 0] = f.x; id[u * 4 + 0] = base + 0;
        v[u * 4 + 1] = f.y; id[u * 4 + 1] = base + 1;
        v[u * 4 + 2] = f.z; id[u * 4 + 2] = base + 2;
        v[u * 4 + 3] = f.w; id[u * 4 + 3] = base + 3;
    }
    for (int k = 0; k < KTOP; ++k) {
        float bv = v[0];
        int bi = id[0];
#pragma unroll
        for (int u = 1; u < 16; ++u)
            if (v[u] > bv || (v[u] == bv && id[u] < bi)) { bv = v[u]; bi = id[u]; }
#pragma unroll
        for (int o = 1; o < 64; o <<= 1) {
            float ov = __shfl_xor(bv, o, 64);
            int oi = __shfl_xor(bi, o, 64);
            if (ov > bv || (ov == bv && oi < bi)) { bv = ov; bi = oi; }
        }
        if (lane == 0) { wvs[wid] = bv; wis[wid] = bi; }
        __syncthreads();
        bv = wvs[0]; bi = wis[0];
#pragma unroll
        for (int ww = 1; ww < 4; ++ww) {
            float ov = wvs[ww];
            int oi = wis[ww];
            if (ov > bv || (ov == bv && oi < bi)) { bv = ov; bi = oi; }
        }
        if (t == 0) {
            vals[i * KTOP + k] = isnan(bv) ? 0.f : bv;
            idxo[i * KTOP + k] = bi;
        }
#pragma unroll
        for (int u = 0; u < 16; ++u)
            if (id[u] == bi) v[u] = -INFINITY;
        __syncthreads();
    }
}

// ---------------- sparse W construction ----------------
__global__ __launch_bounds__(256) void count_indeg(const int* __restrict__ idx, int* __restrict__ cnt) {
    int e = blockIdx.x * 256 + threadIdx.x;
    if (e < NEDGE) atomicAdd(&cnt[idx[e]], 1);
}

__global__ __launch_bounds__(256) void scan_kernel(const int* __restrict__ cnt, int* __restrict__ ptr) {
    __shared__ int tmp[256];
    int t = threadIdx.x;
    int base = t * 16;
    int local[16]; int s = 0;
#pragma unroll
    for (int u = 0; u < 16; ++u) { local[u] = s; s += cnt[base + u]; }
    tmp[t] = s;
    __syncthreads();
    for (int off = 1; off < 256; off <<= 1) {
        int v = (t >= off) ? tmp[t - off] : 0;
        __syncthreads();
        tmp[t] += v;
        __syncthreads();
    }
    int prefix = (t > 0) ? tmp[t - 1] : 0;
#pragma unroll
    for (int u = 0; u < 16; ++u) ptr[base + u] = prefix + local[u];
    if (t == 255) ptr[NN_NODES] = prefix + s;
}

__global__ __launch_bounds__(256) void fill_rev(const int* __restrict__ idx, const float* __restrict__ vals,
                                                const int* __restrict__ ptr, int* __restrict__ fcnt,
                                                int* __restrict__ rrow, int* __restrict__ rsrc,
                                                float* __restrict__ rval) {
    int e = blockIdx.x * 256 + threadIdx.x;
    if (e >= NEDGE) return;
    int i = e / KTOP;
    int j = idx[e];
    int p = ptr[j] + atomicAdd(&fcnt[j], 1);
    rrow[p] = j; rsrc[p] = i; rval[p] = vals[e];
}

__global__ __launch_bounds__(256) void wfwd_kernel(const int* __restrict__ idx, const float* __restrict__ vals,
                                                   float* __restrict__ wfwd) {
    int e = blockIdx.x * 256 + threadIdx.x;
    if (e >= NEDGE) return;
    int i = e / KTOP;
    int j = idx[e];
    float a = vals[e];
    float c = 1.0f;
    const int* lj = &idx[j * KTOP];
#pragma unroll
    for (int k = 0; k < KTOP; ++k)
        if (lj[k] == i) { a += vals[j * KTOP + k]; c = 2.0f; }
    float w = a / c;
    wfwd[e] = w > 0.f ? w : 0.f;
}

__global__ __launch_bounds__(256) void wrev_kernel(const int* __restrict__ idx,
                                                   const int* __restrict__ rrow, const int* __restrict__ rsrc,
                                                   const float* __restrict__ rval, float* __restrict__ wrev) {
    int e = blockIdx.x * 256 + threadIdx.x;
    if (e >= NEDGE) return;
    int i = rrow[e], s = rsrc[e];
    const int* li = &idx[i * KTOP];
    bool dup = false;
#pragma unroll
    for (int k = 0; k < KTOP; ++k)
        if (li[k] == s) dup = true;
    float w = dup ? 0.f : fmaxf(rval[e], 0.f);
    wrev[e] = w;
}

// out[i,:] = act(sum_j W[i,j]*X[j,:] + bias)
__global__ __launch_bounds__(256) void spmm_kernel(float* __restrict__ out, const float* __restrict__ X,
                                                   const int* __restrict__ idx, const float* __restrict__ wfwd,
                                                   const int* __restrict__ ptr, const int* __restrict__ rsrc,
                                                   const float* __restrict__ wrev,
                                                   const float* __restrict__ bias, int act) {
    int i = blockIdx.x, c = threadIdx.x;
    float acc = 0.f;
#pragma unroll
    for (int k = 0; k < KTOP; ++k) {
        int j = idx[i * KTOP + k];
        float w = wfwd[i * KTOP + k];
        acc += w * X[(size_t)j * D_H + c];
    }
    int p1 = ptr[i + 1];
    for (int p = ptr[i]; p < p1; ++p) {
        float w = wrev[p];
        if (w != 0.f) acc += w * X[(size_t)rsrc[p] * D_H + c];
    }
    acc += bias[c];
    if (act == 1) acc = fmaxf(acc, 0.f);
    else acc = acc > 0.f ? acc : expm1f(acc);
    out[(size_t)i * D_H + c] = acc;
}

// pf/pb edge-parallel (W symmetric); prob = exp(5 s)/zrow (no max needed, |s|<=1)
__global__ __launch_bounds__(256) void pfpb_edges(const float* __restrict__ S,
                                                  const int* __restrict__ rows_arr,
                                                  const int* __restrict__ cols,
                                                  const float* __restrict__ w,
                                                  const float* __restrict__ zrow,
                                                  float* __restrict__ pf, float* __restrict__ pb,
                                                  int fwd) {
    int e = blockIdx.x * 256 + threadIdx.x;
    if (e >= NEDGE) return;
    int i, j;
    if (fwd) { i = e / KTOP; j = cols[e]; }
    else { i = rows_arr[e]; j = cols[e]; }
    float wv = w[e];
    if (wv == 0.f) return;
    float sf = S[(size_t)i * NN_NODES + j];
    float sbk = S[(size_t)j * NN_NODES + i];
    float pfv = expf(sf * INV_TEMP) / zrow[i] * wv;
    float pbv = expf(sbk * INV_TEMP) / zrow[j] * wv;
    atomicAdd(&pf[i], pfv);
    atomicAdd(&pb[i], pbv);
}

__global__ __launch_bounds__(256) void loss_kernel(const float* __restrict__ S,
                                                   const float* __restrict__ zrow,
                                                   const float* __restrict__ pf,
                                                   const float* __restrict__ pb,
                                                   float* __restrict__ out) {
    __shared__ float sb[4];
    int t = threadIdx.x;
    float s = 0.f;
    for (int i = t; i < NN_NODES; i += 256) {
        float p = expf(INV_TEMP * S[(size_t)i * NN_NODES + i]) / zrow[i];
        s += -logf(fmaxf(p, EPSV));
        s += 0.5f * (-logf(fmaxf(pf[i], EPSV)) - logf(fmaxf(pb[i], EPSV)));
    }
    float tot = block_reduce_sum(s, sb);
    if (t == 0) out[0] = tot / (float)NN_NODES;
}

// ---------------- launch ----------------
extern "C" void kernel_launch(void* const* d_in, const int* in_sizes, int n_in,
                              void* d_out, int out_size, void* d_ws, size_t ws_size,
                              hipStream_t stream) {
    (void)n_in; (void)out_size; (void)ws_size;
    const float* x = (const float*)d_in[0];
    const int* esrc = (const int*)d_in[1];
    const int* edst = (const int*)d_in[2];
    const float* p_feat = (const float*)d_in[3];
    const float* p_shared = (const float*)d_in[4];
    const float* p_balance = (const float*)d_in[5];
    const float* W1 = (const float*)d_in[6];
    const float* b1 = (const float*)d_in[7];
    const float* W2 = (const float*)d_in[8];
    const float* b2 = (const float*)d_in[9];
    const int E = in_sizes[1];

    float* ws = (float*)d_ws;
    size_t off = 0;
    float* SIM = ws + off; off += (size_t)NN_NODES * NN_NODES;
    float* X1  = ws + off; off += (size_t)NN_NODES * D_IN;
    float* AGG = ws + off; off += (size_t)NN_NODES * D_IN;
    float* T1  = ws + off; off += (size_t)NN_NODES * D_H;
    float* H1  = ws + off; off += (size_t)NN_NODES * D_H;
    float* T2  = ws + off; off += (size_t)NN_NODES * D_H;
    float* Z1  = ws + off; off += (size_t)NN_NODES * D_H;
    float* G1  = ws + off; off += (size_t)NN_NODES * D_H;
    float* Z2  = ws + off; off += (size_t)NN_NODES * D_H;
    float* DINV = ws + off; off += NN_NODES;
    float* VALS = ws + off; off += (size_t)NEDGE;
    int*   IDX  = (int*)(ws + off); off += (size_t)NEDGE;
    float* WFWD = ws + off; off += (size_t)NEDGE;
    int*   RPTR = (int*)(ws + off); off += NN_NODES + 1;
    int*   FCNT = (int*)(ws + off); off += NN_NODES;
    int*   RROW = (int*)(ws + off); off += (size_t)NEDGE;
    int*   RSRC = (int*)(ws + off); off += (size_t)NEDGE;
    float* RVAL = ws + off; off += (size_t)NEDGE;
    float* WREV = ws + off; off += (size_t)NEDGE;
    float* ZROW = ws + off; off += NN_NODES;
    float* PF = ws + off; off += NN_NODES;
    float* PB = ws + off; off += NN_NODES;
    unsigned short* HNhi = (unsigned short*)(ws + off); off += (size_t)NN_NODES * D_H / 2;
    unsigned short* HNlo = (unsigned short*)(ws + off); off += (size_t)NN_NODES * D_H / 2;
    unsigned short* Z1hi = (unsigned short*)(ws + off); off += (size_t)NN_NODES * D_H / 2;
    unsigned short* Z1lo = (unsigned short*)(ws + off); off += (size_t)NN_NODES * D_H / 2;
    unsigned short* Z2hi = (unsigned short*)(ws + off); off += (size_t)NN_NODES * D_H / 2;
    unsigned short* Z2lo = (unsigned short*)(ws + off); off += (size_t)NN_NODES * D_H / 2;
    int* ECNT = (int*)(ws + off); off += NN_NODES;
    int* EPTR = (int*)(ws + off); off += NN_NODES + 1;
    int* ESRT = (int*)(ws + off); off += (size_t)E;

    const int EB = (NEDGE + 255) / 256;
    const int NB = (NN_NODES + 255) / 256;
    const int EBi = (E + 255) / 256;

    // 1. x1
    x1_kernel<<<(NN_NODES * D_IN + 255) / 256, 256, 0, stream>>>(x, p_feat, p_shared, X1);
    // 2. degrees -> dinv, input-graph CSR
    deg_init<<<NB, 256, 0, stream>>>(DINV);
    deg_edges<<<512, 256, 0, stream>>>(DINV, edst, E);
    to_dinv<<<NB, 256, 0, stream>>>(DINV);
    zero_i<<<NB, 256, 0, stream>>>(ECNT, NN_NODES);
    ecount_kernel<<<EBi, 256, 0, stream>>>(edst, ECNT, E);
    scan_kernel<<<1, 256, 0, stream>>>(ECNT, EPTR);
    zero_i<<<NB, 256, 0, stream>>>(ECNT, NN_NODES);
    efill_kernel<<<EBi, 256, 0, stream>>>(esrc, edst, EPTR, ECNT, ESRT, E);
    // 3. agg = A_norm @ x1  (gather)
    prop_gather<<<NN_NODES, D_IN, 0, stream>>>(AGG, X1, DINV, EPTR, ESRT, nullptr, D_IN, 0);
    // 4. h, hn (bf16 hi/lo)
    h_hn_kernel<<<NN_NODES, 256, 0, stream>>>(X1, AGG, p_balance, HNhi, HNlo);
    // 5. sim = hn @ hn^T  (MFMA split-bf16)
    {
        dim3 g(NN_NODES / 128, NN_NODES / 128);
        gemm_nt_mfma<<<g, 256, 0, stream>>>(HNhi, HNlo, HNhi, HNlo, SIM, nullptr);
    }
    // 6. topk
    topk_kernel<<<NN_NODES, 256, 0, stream>>>(SIM, VALS, IDX);
    // 7. sparse W: reverse CSR + edge weights
    zero_i<<<NB, 256, 0, stream>>>(FCNT, NN_NODES);
    count_indeg<<<EB, 256, 0, stream>>>(IDX, FCNT);
    scan_kernel<<<1, 256, 0, stream>>>(FCNT, RPTR);
    zero_i<<<NB, 256, 0, stream>>>(FCNT, NN_NODES);
    fill_rev<<<EB, 256, 0, stream>>>(IDX, VALS, RPTR, FCNT, RROW, RSRC, RVAL);
    wfwd_kernel<<<EB, 256, 0, stream>>>(IDX, VALS, WFWD);
    wrev_kernel<<<EB, 256, 0, stream>>>(IDX, RROW, RSRC, RVAL, WREV);
    // 8. t1 = x1 @ W1
    {
        dim3 g(D_H / BN, NN_NODES / BM);
        gemm_nn_kernel<<<g, 256, 0, stream>>>(X1, W1, T1, NN_NODES, D_H, D_IN, nullptr, 0);
    }
    // 9. h1 = relu(prop(t1) + b1)  (gather, fused bias+relu)
    prop_gather<<<NN_NODES, D_H, 0, stream>>>(H1, T1, DINV, EPTR, ESRT, b1, D_H, 1);
    // 10. z1 = elu(prop(h1@W2) + b2)
    {
        dim3 g(D_H / BN, NN_NODES / BM);
        gemm_nn_kernel<<<g, 256, 0, stream>>>(H1, W2, T2, NN_NODES, D_H, D_H, nullptr, 0);
    }
    prop_gather<<<NN_NODES, D_H, 0, stream>>>(Z1, T2, DINV, EPTR, ESRT, b2, D_H, 2);
    // 11. g1 = relu(W @ t1 + b1)   [sparse]
    spmm_kernel<<<NN_NODES, 256, 0, stream>>>(G1, T1, IDX, WFWD, RPTR, RSRC, WREV, b1, 1);
    // 12. g2 = g1 @ W2 (into T2)
    {
        dim3 g(D_H / BN, NN_NODES / BM);
        gemm_nn_kernel<<<g, 256, 0, stream>>>(G1, W2, T2, NN_NODES, D_H, D_H, nullptr, 0);
    }
    // 13. z2 = elu(W @ g2 + b2)   [sparse]
    spmm_kernel<<<NN_NODES, 256, 0, stream>>>(Z2, T2, IDX, WFWD, RPTR, RSRC, WREV, b2, 2);
    // 14. normalize z1, z2 -> bf16 hi/lo
    rownorm_kernel<<<NN_NODES, 256, 0, stream>>>(Z1, Z1hi, Z1lo);
    rownorm_kernel<<<NN_NODES, 256, 0, stream>>>(Z2, Z2hi, Z2lo);
    // 15. S = z1n @ z2n^T (MFMA split-bf16) with fused exp row-sum -> ZROW
    zero_f<<<NB, 256, 0, stream>>>(ZROW, NN_NODES);
    {
        dim3 g(NN_NODES / 128, NN_NODES / 128);
        gemm_nt_mfma<<<g, 256, 0, stream>>>(Z1hi, Z1lo, Z2hi, Z2lo, SIM, ZROW);
    }
    // 16. pf / pb (sparse, edge-parallel)
    zero_f<<<NB, 256, 0, stream>>>(PF, NN_NODES);
    zero_f<<<NB, 256, 0, stream>>>(PB, NN_NODES);
    pfpb_edges<<<EB, 256, 0, stream>>>(SIM, nullptr, IDX, WFWD, ZROW, PF, PB, 1);
    pfpb_edges<<<EB, 256, 0, stream>>>(SIM, RROW, RSRC, WREV, ZROW, PF, PB, 0);
    // 17. loss (diag from SIM + ZROW)
    loss_kernel<<<1, 256, 0, stream>>>(SIM, ZROW, PF, PB, (float*)d_out);
}

// Round 9
// 524.199 us; speedup vs baseline: 1.1029x; 1.0705x over previous
//
#include <hip/hip_runtime.h>
#include <math.h>

#define NN_NODES 4096
#define D_IN 128
#define D_H 256
#define KTOP 17
#define NEDGE (NN_NODES * KTOP)
#define INV_TEMP 5.0f
#define EPSV 1e-8f

typedef __bf16 bf16x8 __attribute__((ext_vector_type(8)));
typedef float f32x4 __attribute__((ext_vector_type(4)));

// ---------------- helpers ----------------
__device__ __forceinline__ float block_reduce_sum(float v, float* sb) {
#pragma unroll
    for (int o = 32; o > 0; o >>= 1) v += __shfl_down(v, o, 64);
    int wid = threadIdx.x >> 6;
    __syncthreads();
    if ((threadIdx.x & 63) == 0) sb[wid] = v;
    __syncthreads();
    return sb[0] + sb[1] + sb[2] + sb[3];
}

// split fp32 into bf16 hi + bf16 lo (RNE both)
__device__ __forceinline__ void f2hilo(float x, unsigned short* h, unsigned short* l) {
    unsigned u = __float_as_uint(x);
    unsigned r = u + 0x7fff + ((u >> 16) & 1);
    unsigned short hh = (unsigned short)(r >> 16);
    float hf = __uint_as_float((unsigned)hh << 16);
    float lo = x - hf;
    unsigned ul = __float_as_uint(lo);
    unsigned rl = ul + 0x7fff + ((ul >> 16) & 1);
    *h = hh;
    *l = (unsigned short)(rl >> 16);
}

// ---------------- elementwise / setup ----------------
__global__ __launch_bounds__(256) void zero_f(float* p, int n) {
    int i = blockIdx.x * 256 + threadIdx.x;
    if (i < n) p[i] = 0.f;
}

__global__ __launch_bounds__(256) void zero_i(int* p, int n) {
    int i = blockIdx.x * 256 + threadIdx.x;
    if (i < n) p[i] = 0;
}

__global__ __launch_bounds__(256) void x1_kernel(const float* __restrict__ x,
                                                 const float* __restrict__ p_feat,
                                                 const float* __restrict__ p_shared,
                                                 float* __restrict__ x1) {
    int i = blockIdx.x * 256 + threadIdx.x;
    if (i >= NN_NODES * D_IN) return;
    int c = i & (D_IN - 1);
    float v = x[i] * p_feat[c];
    v = fmaxf(v, 0.0f) * p_shared[c];
    x1[i] = v;
}

// dinv[i] = rsqrt(1 + indegree[i])   (self-loop included)
__global__ __launch_bounds__(256) void to_dinv(const int* __restrict__ cnt, float* __restrict__ dinv) {
    int i = blockIdx.x * 256 + threadIdx.x;
    if (i < NN_NODES) dinv[i] = rsqrtf(1.0f + (float)cnt[i]);
}

// ---------------- input-graph CSR (keyed by dst) ----------------
__global__ __launch_bounds__(256) void ecount_kernel(const int* __restrict__ dst, int* __restrict__ cnt, int E) {
    int e = blockIdx.x * 256 + threadIdx.x;
    if (e < E) atomicAdd(&cnt[dst[e]], 1);
}

__global__ __launch_bounds__(256) void efill_kernel(const int* __restrict__ src, const int* __restrict__ dst,
                                                    const int* __restrict__ ptr, int* __restrict__ cnt,
                                                    int* __restrict__ esrt, int E) {
    int e = blockIdx.x * 256 + threadIdx.x;
    if (e >= E) return;
    int d = dst[e];
    int p = ptr[d] + atomicAdd(&cnt[d], 1);
    esrt[p] = src[e];
}

// out[n][c] = act( dinv[n]^2*h[n][c] + sum_{edges s->n} dinv[s]*dinv[n]*h[s][c] + bias[c] )
__global__ void prop_gather(float* __restrict__ out, const float* __restrict__ h,
                            const float* __restrict__ dinv, const int* __restrict__ eptr,
                            const int* __restrict__ esrt, const float* __restrict__ bias,
                            int C, int act) {
    int n = blockIdx.x, t = threadIdx.x;
    float dn = dinv[n];
    float acc = dn * dn * h[(size_t)n * C + t];
    int p1 = eptr[n + 1];
    for (int p = eptr[n]; p < p1; ++p) {
        int s = esrt[p];
        acc += dinv[s] * dn * h[(size_t)s * C + t];
    }
    if (bias) acc += bias[t];
    if (act == 1) acc = fmaxf(acc, 0.f);
    else if (act == 2) acc = acc > 0.f ? acc : expm1f(acc);
    out[(size_t)n * C + t] = acc;
}

// h = concat(x1, agg)*p_balance; hn = h/(||h||+eps) -> bf16 hi/lo. block/row.
__global__ __launch_bounds__(256) void h_hn_kernel(const float* __restrict__ x1,
                                                   const float* __restrict__ agg,
                                                   const float* __restrict__ p_balance,
                                                   unsigned short* __restrict__ hn_hi,
                                                   unsigned short* __restrict__ hn_lo) {
    __shared__ float sb[4];
    int n = blockIdx.x, t = threadIdx.x;
    float v;
    if (t < D_IN) v = x1[(size_t)n * D_IN + t] * p_balance[t];
    else v = agg[(size_t)n * D_IN + (t - D_IN)] * p_balance[t];
    float ss = block_reduce_sum(v * v, sb);
    float inv = 1.0f / (sqrtf(ss) + EPSV);
    unsigned short h, l;
    f2hilo(v * inv, &h, &l);
    hn_hi[(size_t)n * D_H + t] = h;
    hn_lo[(size_t)n * D_H + t] = l;
}

// row normalize Z (C=256) -> bf16 hi/lo (Z unchanged)
__global__ __launch_bounds__(256) void rownorm_kernel(const float* __restrict__ Z,
                                                      unsigned short* __restrict__ zhi,
                                                      unsigned short* __restrict__ zlo) {
    __shared__ float sb[4];
    int n = blockIdx.x, t = threadIdx.x;
    float v = Z[(size_t)n * D_H + t];
    float ss = block_reduce_sum(v * v, sb);
    float inv = 1.0f / (sqrtf(ss) + EPSV);
    unsigned short h, l;
    f2hilo(v * inv, &h, &l);
    zhi[(size_t)n * D_H + t] = h;
    zlo[(size_t)n * D_H + t] = l;
}

// ---------------- fp32 GEMM (small NN cases) ----------------
#define BM 64
#define BN 64
#define BK 16

__global__ __launch_bounds__(256) void gemm_nn_kernel(const float* __restrict__ A,
                                                      const float* __restrict__ B,
                                                      float* __restrict__ C, int M, int Nn,
                                                      int Kk, const float* __restrict__ bias,
                                                      int ep) {
    __shared__ float As[BK][BM + 4];
    __shared__ float Bs[BK][BN + 4];
    const int tid = threadIdx.x;
    const int tx = tid & 15, ty = tid >> 4;
    const int m0 = blockIdx.y * BM, n0 = blockIdx.x * BN;
    const int arow = tid >> 2, acol = (tid & 3) << 2;
    const int brow = tid >> 4, bcol = (tid & 15) << 2;
    float acc[4][4] = {{0.f}};

    for (int k0 = 0; k0 < Kk; k0 += BK) {
        float4 av = *(const float4*)&A[(size_t)(m0 + arow) * Kk + k0 + acol];
        float4 bv = *(const float4*)&B[(size_t)(k0 + brow) * Nn + n0 + bcol];
        As[acol + 0][arow] = av.x;
        As[acol + 1][arow] = av.y;
        As[acol + 2][arow] = av.z;
        As[acol + 3][arow] = av.w;
        *(float4*)&Bs[brow][bcol] = bv;
        __syncthreads();
#pragma unroll
        for (int k = 0; k < BK; ++k) {
            float4 a = *(const float4*)&As[k][ty << 2];
            float4 b = *(const float4*)&Bs[k][tx << 2];
            acc[0][0] += a.x * b.x; acc[0][1] += a.x * b.y; acc[0][2] += a.x * b.z; acc[0][3] += a.x * b.w;
            acc[1][0] += a.y * b.x; acc[1][1] += a.y * b.y; acc[1][2] += a.y * b.z; acc[1][3] += a.y * b.w;
            acc[2][0] += a.z * b.x; acc[2][1] += a.z * b.y; acc[2][2] += a.z * b.z; acc[2][3] += a.z * b.w;
            acc[3][0] += a.w * b.x; acc[3][1] += a.w * b.y; acc[3][2] += a.w * b.z; acc[3][3] += a.w * b.w;
        }
        __syncthreads();
    }
    float bb[4] = {0.f, 0.f, 0.f, 0.f};
    if (ep) {
#pragma unroll
        for (int j = 0; j < 4; ++j) bb[j] = bias[n0 + (tx << 2) + j];
    }
#pragma unroll
    for (int i = 0; i < 4; ++i) {
        int m = m0 + (ty << 2) + i;
        float r[4];
#pragma unroll
        for (int j = 0; j < 4; ++j) {
            float v = acc[i][j] + bb[j];
            if (ep == 1) v = fmaxf(v, 0.0f);
            else if (ep == 2) v = v > 0.0f ? v : expm1f(v);
            r[j] = v;
        }
        *(float4*)&C[(size_t)m * Nn + n0 + (tx << 2)] = *(float4*)r;
    }
}

// ---------------- MFMA NT GEMM: C[4096,4096] = X @ Y^T, K=256, split-bf16 ----------------
// If zrow != nullptr, also accumulates row sums of exp(INV_TEMP * C) into zrow.
__global__ __launch_bounds__(256) void gemm_nt_mfma(const unsigned short* __restrict__ Ahi,
                                                    const unsigned short* __restrict__ Alo,
                                                    const unsigned short* __restrict__ Bhi,
                                                    const unsigned short* __restrict__ Blo,
                                                    float* __restrict__ C,
                                                    float* __restrict__ zrow) {
    __shared__ unsigned short lds[4 * 16 * 512];  // 64 KB
    const int tid = threadIdx.x;
    const int w = tid >> 6, lane = tid & 63;
    const int m0 = blockIdx.y * 128, n0 = blockIdx.x * 128;
    const int wmt = (w >> 1) * 4;
    const int wnt = (w & 1) * 4;

    f32x4 acc[4][4];
#pragma unroll
    for (int i = 0; i < 4; ++i)
#pragma unroll
        for (int j = 0; j < 4; ++j) acc[i][j] = (f32x4)(0.f);

    unsigned short* Ah = lds;
    unsigned short* Al = lds + 8192;
    unsigned short* Bh = lds + 16384;
    unsigned short* Bl = lds + 24576;

    const unsigned short* srcs[4] = {Ahi, Alo, Bhi, Blo};
    unsigned short* dsts[4] = {Ah, Al, Bh, Bl};

    const int lrow = lane & 15, lquad = lane >> 4;

    for (int k0 = 0; k0 < 256; k0 += 64) {
#pragma unroll
        for (int arr = 0; arr < 4; ++arr) {
            const unsigned short* src = srcs[arr];
            unsigned short* dst = dsts[arr];
            const int base0 = (arr < 2) ? m0 : n0;
#pragma unroll
            for (int ti = 0; ti < 4; ++ti) {
                int t = w + ti * 4;
                int row = base0 + (t & 7) * 16 + lrow;
                int kk = k0 + (t >> 3) * 32 + lquad * 8;
                uint4 v = *(const uint4*)&src[(size_t)row * 256 + kk];
                *(uint4*)&dst[t * 512 + lane * 8] = v;
            }
        }
        __syncthreads();
#pragma unroll
        for (int ksub = 0; ksub < 2; ++ksub) {
            bf16x8 ah[4], al[4], bh[4], bl[4];
#pragma unroll
            for (int i = 0; i < 4; ++i) {
                ah[i] = __builtin_bit_cast(bf16x8, *(const uint4*)&Ah[(ksub * 8 + wmt + i) * 512 + lane * 8]);
                al[i] = __builtin_bit_cast(bf16x8, *(const uint4*)&Al[(ksub * 8 + wmt + i) * 512 + lane * 8]);
                bh[i] = __builtin_bit_cast(bf16x8, *(const uint4*)&Bh[(ksub * 8 + wnt + i) * 512 + lane * 8]);
                bl[i] = __builtin_bit_cast(bf16x8, *(const uint4*)&Bl[(ksub * 8 + wnt + i) * 512 + lane * 8]);
            }
#pragma unroll
            for (int i = 0; i < 4; ++i)
#pragma unroll
                for (int j = 0; j < 4; ++j) {
                    acc[i][j] = __builtin_amdgcn_mfma_f32_16x16x32_bf16(ah[i], bh[j], acc[i][j], 0, 0, 0);
                    acc[i][j] = __builtin_amdgcn_mfma_f32_16x16x32_bf16(ah[i], bl[j], acc[i][j], 0, 0, 0);
                    acc[i][j] = __builtin_amdgcn_mfma_f32_16x16x32_bf16(al[i], bh[j], acc[i][j], 0, 0, 0);
                }
        }
        __syncthreads();
    }
    const int col = lane & 15, rq = (lane >> 4) * 4;
#pragma unroll
    for (int i = 0; i < 4; ++i) {
        int rb = m0 + (wmt + i) * 16 + rq;
#pragma unroll
        for (int j = 0; j < 4; ++j) {
            int cb = n0 + (wnt + j) * 16 + col;
#pragma unroll
            for (int r = 0; r < 4; ++r)
                C[(size_t)(rb + r) * NN_NODES + cb] = acc[i][j][r];
        }
    }
    if (zrow) {
#pragma unroll
        for (int i = 0; i < 4; ++i) {
            int rb = m0 + (wmt + i) * 16 + rq;
#pragma unroll
            for (int r = 0; r < 4; ++r) {
                float s = 0.f;
#pragma unroll
                for (int j = 0; j < 4; ++j) s += __expf(INV_TEMP * acc[i][j][r]);
#pragma unroll
                for (int o = 1; o < 16; o <<= 1) s += __shfl_xor(s, o, 64);
                if ((lane & 15) == 0) atomicAdd(&zrow[rb + r], s);
            }
        }
    }
}

// ---------------- top-k: round-6 structure + cached per-thread candidate ----------------
// Each thread caches its best-of-16 across rounds; per round only butterfly +
// 4-entry combine; only the unique owner thread rescans. Parity-double-buffered
// winner slots -> 1 barrier per round.
__global__ __launch_bounds__(256) void topk_kernel(const float* __restrict__ S,
                                                   float* __restrict__ vals,
                                                   int* __restrict__ idxo) {
    __shared__ float wvs[8];
    __shared__ int wis[8];
    const int i = blockIdx.x, t = threadIdx.x;
    const int lane = t & 63, wid = t >> 6;
    const float* row = &S[(size_t)i * NN_NODES];
    float v[16];
    int id[16];
#pragma unroll
    for (int u = 0; u < 4; ++u) {
        int base = u * 1024 + t * 4;
        float4 f = *(const float4*)&row[base];
        v[u * 4 + 0] = f.x; id[u * 4 + 0] = base + 0;
        v[u * 4 + 1] = f.y; id[u * 4 + 1] = base + 1;
        v[u * 4 + 2] = f.z; id[u * 4 + 2] = base + 2;
        v[u * 4 + 3] = f.w; id[u * 4 + 3] = base + 3;
    }
    float bv = v[0];
    int bi = id[0];
#pragma unroll
    for (int u = 1; u < 16; ++u)
        if (v[u] > bv || (v[u] == bv && id[u] < bi)) { bv = v[u]; bi = id[u]; }

    for (int k = 0; k < KTOP; ++k) {
        float mv = bv;
        int mi = bi;
#pragma unroll
        for (int o = 1; o < 64; o <<= 1) {
            float ov = __shfl_xor(mv, o, 64);
            int oi = __shfl_xor(mi, o, 64);
            if (ov > mv || (ov == mv && oi < mi)) { mv = ov; mi = oi; }
        }
        int slot = ((k & 1) << 2) + wid;
        if (lane == 0) { wvs[slot] = mv; wis[slot] = mi; }
        __syncthreads();
        int b0 = (k & 1) << 2;
        mv = wvs[b0]; mi = wis[b0];
#pragma unroll
        for (int ww = 1; ww < 4; ++ww) {
            float ov = wvs[b0 + ww];
            int oi = wis[b0 + ww];
            if (ov > mv || (ov == mv && oi < mi)) { mv = ov; mi = oi; }
        }
        if (t == 0) {
            vals[i * KTOP + k] = isnan(mv) ? 0.f : mv;
            idxo[i * KTOP + k] = mi;
        }
        if (bi == mi) {  // unique owner: invalidate + rescan its 16
#pragma unroll
            for (int u = 0; u < 16; ++u)
                if (id[u] == mi) v[u] = -INFINITY;
            bv = v[0]; bi = id[0];
#pragma unroll
            for (int u = 1; u < 16; ++u)
                if (v[u] > bv || (v[u] == bv && id[u] < bi)) { bv = v[u]; bi = id[u]; }
        }
    }
}

// ---------------- sparse W construction ----------------
__global__ __launch_bounds__(256) void count_indeg(const int* __restrict__ idx, int* __restrict__ cnt) {
    int e = blockIdx.x * 256 + threadIdx.x;
    if (e < NEDGE) atomicAdd(&cnt[idx[e]], 1);
}

// exclusive scan of 4096 counts -> ptr[4097]; zeroes cnt after reading.
__global__ __launch_bounds__(256) void scan_kernel(int* __restrict__ cnt, int* __restrict__ ptr) {
    __shared__ int tmp[256];
    int t = threadIdx.x;
    int base = t * 16;
    int local[16]; int s = 0;
#pragma unroll
    for (int u = 0; u < 16; ++u) { local[u] = s; s += cnt[base + u]; }
#pragma unroll
    for (int u = 0; u < 16; ++u) cnt[base + u] = 0;
    tmp[t] = s;
    __syncthreads();
    for (int off = 1; off < 256; off <<= 1) {
        int v = (t >= off) ? tmp[t - off] : 0;
        __syncthreads();
        tmp[t] += v;
        __syncthreads();
    }
    int prefix = (t > 0) ? tmp[t - 1] : 0;
#pragma unroll
    for (int u = 0; u < 16; ++u) ptr[base + u] = prefix + local[u];
    if (t == 255) ptr[NN_NODES] = prefix + s;
}

__global__ __launch_bounds__(256) void fill_rev(const int* __restrict__ idx, const float* __restrict__ vals,
                                                const int* __restrict__ ptr, int* __restrict__ fcnt,
                                                int* __restrict__ rrow, int* __restrict__ rsrc,
                                                float* __restrict__ rval) {
    int e = blockIdx.x * 256 + threadIdx.x;
    if (e >= NEDGE) return;
    int i = e / KTOP;
    int j = idx[e];
    int p = ptr[j] + atomicAdd(&fcnt[j], 1);
    rrow[p] = j; rsrc[p] = i; rval[p] = vals[e];
}

// fused fwd+rev edge weights (grid covers 2*NEDGE)
__global__ __launch_bounds__(256) void wedges_kernel(const int* __restrict__ idx, const float* __restrict__ vals,
                                                     const int* __restrict__ rrow, const int* __restrict__ rsrc,
                                                     const float* __restrict__ rval,
                                                     float* __restrict__ wfwd, float* __restrict__ wrev) {
    int e = blockIdx.x * 256 + threadIdx.x;
    if (e < NEDGE) {
        int i = e / KTOP;
        int j = idx[e];
        float a = vals[e];
        float c = 1.0f;
        const int* lj = &idx[j * KTOP];
#pragma unroll
        for (int k = 0; k < KTOP; ++k)
            if (lj[k] == i) { a += vals[j * KTOP + k]; c = 2.0f; }
        float w = a / c;
        wfwd[e] = w > 0.f ? w : 0.f;
    } else if (e < 2 * NEDGE) {
        int e2 = e - NEDGE;
        int i = rrow[e2], s = rsrc[e2];
        const int* li = &idx[i * KTOP];
        bool dup = false;
#pragma unroll
        for (int k = 0; k < KTOP; ++k)
            if (li[k] == s) dup = true;
        wrev[e2] = dup ? 0.f : fmaxf(rval[e2], 0.f);
    }
}

// out[i,:] = act(sum_j W[i,j]*X[j,:] + bias)
__global__ __launch_bounds__(256) void spmm_kernel(float* __restrict__ out, const float* __restrict__ X,
                                                   const int* __restrict__ idx, const float* __restrict__ wfwd,
                                                   const int* __restrict__ ptr, const int* __restrict__ rsrc,
                                                   const float* __restrict__ wrev,
                                                   const float* __restrict__ bias, int act) {
    int i = blockIdx.x, c = threadIdx.x;
    float acc = 0.f;
#pragma unroll
    for (int k = 0; k < KTOP; ++k) {
        int j = idx[i * KTOP + k];
        float w = wfwd[i * KTOP + k];
        acc += w * X[(size_t)j * D_H + c];
    }
    int p1 = ptr[i + 1];
    for (int p = ptr[i]; p < p1; ++p) {
        float w = wrev[p];
        if (w != 0.f) acc += w * X[(size_t)rsrc[p] * D_H + c];
    }
    acc += bias[c];
    if (act == 1) acc = fmaxf(acc, 0.f);
    else acc = acc > 0.f ? acc : expm1f(acc);
    out[(size_t)i * D_H + c] = acc;
}

// fused pf/pb over fwd+rev lists (grid covers 2*NEDGE); prob = exp(5 s)/zrow
__global__ __launch_bounds__(256) void pfpb_edges(const float* __restrict__ S,
                                                  const int* __restrict__ idx,
                                                  const float* __restrict__ wfwd,
                                                  const int* __restrict__ rrow,
                                                  const int* __restrict__ rsrc,
                                                  const float* __restrict__ wrev,
                                                  const float* __restrict__ zrow,
                                                  float* __restrict__ pf, float* __restrict__ pb) {
    int e = blockIdx.x * 256 + threadIdx.x;
    if (e >= 2 * NEDGE) return;
    int i, j;
    float wv;
    if (e < NEDGE) { i = e / KTOP; j = idx[e]; wv = wfwd[e]; }
    else { int e2 = e - NEDGE; i = rrow[e2]; j = rsrc[e2]; wv = wrev[e2]; }
    if (wv == 0.f) return;
    float sf = S[(size_t)i * NN_NODES + j];
    float sbk = S[(size_t)j * NN_NODES + i];
    float pfv = expf(sf * INV_TEMP) / zrow[i] * wv;
    float pbv = expf(sbk * INV_TEMP) / zrow[j] * wv;
    atomicAdd(&pf[i], pfv);
    atomicAdd(&pb[i], pbv);
}

__global__ __launch_bounds__(256) void loss_kernel(const float* __restrict__ S,
                                                   const float* __restrict__ zrow,
                                                   const float* __restrict__ pf,
                                                   const float* __restrict__ pb,
                                                   float* __restrict__ out) {
    __shared__ float sb[4];
    int t = threadIdx.x;
    float s = 0.f;
    for (int i = t; i < NN_NODES; i += 256) {
        float p = expf(INV_TEMP * S[(size_t)i * NN_NODES + i]) / zrow[i];
        s += -logf(fmaxf(p, EPSV));
        s += 0.5f * (-logf(fmaxf(pf[i], EPSV)) - logf(fmaxf(pb[i], EPSV)));
    }
    float tot = block_reduce_sum(s, sb);
    if (t == 0) out[0] = tot / (float)NN_NODES;
}

// ---------------- launch ----------------
extern "C" void kernel_launch(void* const* d_in, const int* in_sizes, int n_in,
                              void* d_out, int out_size, void* d_ws, size_t ws_size,
                              hipStream_t stream) {
    (void)n_in; (void)out_size; (void)ws_size;
    const float* x = (const float*)d_in[0];
    const int* esrc = (const int*)d_in[1];
    const int* edst = (const int*)d_in[2];
    const float* p_feat = (const float*)d_in[3];
    const float* p_shared = (const float*)d_in[4];
    const float* p_balance = (const float*)d_in[5];
    const float* W1 = (const float*)d_in[6];
    const float* b1 = (const float*)d_in[7];
    const float* W2 = (const float*)d_in[8];
    const float* b2 = (const float*)d_in[9];
    const int E = in_sizes[1];

    float* ws = (float*)d_ws;
    size_t off = 0;
    float* SIM = ws + off; off += (size_t)NN_NODES * NN_NODES;
    float* X1  = ws + off; off += (size_t)NN_NODES * D_IN;
    float* AGG = ws + off; off += (size_t)NN_NODES * D_IN;
    float* T1  = ws + off; off += (size_t)NN_NODES * D_H;
    float* H1  = ws + off; off += (size_t)NN_NODES * D_H;
    float* T2  = ws + off; off += (size_t)NN_NODES * D_H;
    float* Z1  = ws + off; off += (size_t)NN_NODES * D_H;
    float* G1  = ws + off; off += (size_t)NN_NODES * D_H;
    float* Z2  = ws + off; off += (size_t)NN_NODES * D_H;
    float* DINV = ws + off; off += NN_NODES;
    float* VALS = ws + off; off += (size_t)NEDGE;
    int*   IDX  = (int*)(ws + off); off += (size_t)NEDGE;
    float* WFWD = ws + off; off += (size_t)NEDGE;
    int*   RPTR = (int*)(ws + off); off += NN_NODES + 1;
    int*   FCNT = (int*)(ws + off); off += NN_NODES;
    int*   RROW = (int*)(ws + off); off += (size_t)NEDGE;
    int*   RSRC = (int*)(ws + off); off += (size_t)NEDGE;
    float* RVAL = ws + off; off += (size_t)NEDGE;
    float* WREV = ws + off; off += (size_t)NEDGE;
    float* ZROW = ws + off; off += NN_NODES;   // ZROW,PF,PB contiguous (zeroed together)
    float* PF = ws + off; off += NN_NODES;
    float* PB = ws + off; off += NN_NODES;
    unsigned short* HNhi = (unsigned short*)(ws + off); off += (size_t)NN_NODES * D_H / 2;
    unsigned short* HNlo = (unsigned short*)(ws + off); off += (size_t)NN_NODES * D_H / 2;
    unsigned short* Z1hi = (unsigned short*)(ws + off); off += (size_t)NN_NODES * D_H / 2;
    unsigned short* Z1lo = (unsigned short*)(ws + off); off += (size_t)NN_NODES * D_H / 2;
    unsigned short* Z2hi = (unsigned short*)(ws + off); off += (size_t)NN_NODES * D_H / 2;
    unsigned short* Z2lo = (unsigned short*)(ws + off); off += (size_t)NN_NODES * D_H / 2;
    int* ECNT = (int*)(ws + off); off += NN_NODES;
    int* EPTR = (int*)(ws + off); off += NN_NODES + 1;
    int* ESRT = (int*)(ws + off); off += (size_t)E;

    const int EB = (NEDGE + 255) / 256;
    const int NB = (NN_NODES + 255) / 256;
    const int EBi = (E + 255) / 256;

    // 1. x1
    x1_kernel<<<(NN_NODES * D_IN + 255) / 256, 256, 0, stream>>>(x, p_feat, p_shared, X1);
    // 2. input-graph CSR + dinv (deg = 1 + indegree)
    zero_i<<<NB, 256, 0, stream>>>(ECNT, NN_NODES);
    ecount_kernel<<<EBi, 256, 0, stream>>>(edst, ECNT, E);
    to_dinv<<<NB, 256, 0, stream>>>(ECNT, DINV);
    scan_kernel<<<1, 256, 0, stream>>>(ECNT, EPTR);  // zeroes ECNT for efill
    efill_kernel<<<EBi, 256, 0, stream>>>(esrc, edst, EPTR, ECNT, ESRT, E);
    // zero ZROW/PF/PB (contiguous) early
    zero_f<<<(3 * NN_NODES + 255) / 256, 256, 0, stream>>>(ZROW, 3 * NN_NODES);
    // 3. agg = A_norm @ x1  (gather)
    prop_gather<<<NN_NODES, D_IN, 0, stream>>>(AGG, X1, DINV, EPTR, ESRT, nullptr, D_IN, 0);
    // 4. h, hn (bf16 hi/lo)
    h_hn_kernel<<<NN_NODES, 256, 0, stream>>>(X1, AGG, p_balance, HNhi, HNlo);
    // 5. sim = hn @ hn^T  (MFMA split-bf16)
    {
        dim3 g(NN_NODES / 128, NN_NODES / 128);
        gemm_nt_mfma<<<g, 256, 0, stream>>>(HNhi, HNlo, HNhi, HNlo, SIM, nullptr);
    }
    // 6. topk
    topk_kernel<<<NN_NODES, 256, 0, stream>>>(SIM, VALS, IDX);
    // 7. sparse W: reverse CSR + fused edge weights
    zero_i<<<NB, 256, 0, stream>>>(FCNT, NN_NODES);
    count_indeg<<<EB, 256, 0, stream>>>(IDX, FCNT);
    scan_kernel<<<1, 256, 0, stream>>>(FCNT, RPTR);  // zeroes FCNT for fill_rev
    fill_rev<<<EB, 256, 0, stream>>>(IDX, VALS, RPTR, FCNT, RROW, RSRC, RVAL);
    wedges_kernel<<<2 * EB, 256, 0, stream>>>(IDX, VALS, RROW, RSRC, RVAL, WFWD, WREV);
    // 8. t1 = x1 @ W1
    {
        dim3 g(D_H / BN, NN_NODES / BM);
        gemm_nn_kernel<<<g, 256, 0, stream>>>(X1, W1, T1, NN_NODES, D_H, D_IN, nullptr, 0);
    }
    // 9. h1 = relu(prop(t1) + b1)
    prop_gather<<<NN_NODES, D_H, 0, stream>>>(H1, T1, DINV, EPTR, ESRT, b1, D_H, 1);
    // 10. z1 = elu(prop(h1@W2) + b2)
    {
        dim3 g(D_H / BN, NN_NODES / BM);
        gemm_nn_kernel<<<g, 256, 0, stream>>>(H1, W2, T2, NN_NODES, D_H, D_H, nullptr, 0);
    }
    prop_gather<<<NN_NODES, D_H, 0, stream>>>(Z1, T2, DINV, EPTR, ESRT, b2, D_H, 2);
    // 11. g1 = relu(W @ t1 + b1)   [sparse]
    spmm_kernel<<<NN_NODES, 256, 0, stream>>>(G1, T1, IDX, WFWD, RPTR, RSRC, WREV, b1, 1);
    // 12. g2 = g1 @ W2 (into T2)
    {
        dim3 g(D_H / BN, NN_NODES / BM);
        gemm_nn_kernel<<<g, 256, 0, stream>>>(G1, W2, T2, NN_NODES, D_H, D_H, nullptr, 0);
    }
    // 13. z2 = elu(W @ g2 + b2)   [sparse]
    spmm_kernel<<<NN_NODES, 256, 0, stream>>>(Z2, T2, IDX, WFWD, RPTR, RSRC, WREV, b2, 2);
    // 14. normalize z1, z2 -> bf16 hi/lo
    rownorm_kernel<<<NN_NODES, 256, 0, stream>>>(Z1, Z1hi, Z1lo);
    rownorm_kernel<<<NN_NODES, 256, 0, stream>>>(Z2, Z2hi, Z2lo);
    // 15. S = z1n @ z2n^T (MFMA split-bf16) with fused exp row-sum -> ZROW
    {
        dim3 g(NN_NODES / 128, NN_NODES / 128);
        gemm_nt_mfma<<<g, 256, 0, stream>>>(Z1hi, Z1lo, Z2hi, Z2lo, SIM, ZROW);
    }
    // 16. pf / pb (fused fwd+rev)
    pfpb_edges<<<2 * EB, 256, 0, stream>>>(SIM, IDX, WFWD, RROW, RSRC, WREV, ZROW, PF, PB);
    // 17. loss
    loss_kernel<<<1, 256, 0, stream>>>(SIM, ZROW, PF, PB, (float*)d_out);
}

// Round 10
// 484.759 us; speedup vs baseline: 1.1927x; 1.0814x over previous
//
#include <hip/hip_runtime.h>
#include <math.h>

#define NN_NODES 4096
#define D_IN 128
#define D_H 256
#define KTOP 17
#define NEDGE (NN_NODES * KTOP)
#define INV_TEMP 5.0f
#define EPSV 1e-8f

typedef __bf16 bf16x8 __attribute__((ext_vector_type(8)));
typedef float f32x4 __attribute__((ext_vector_type(4)));

// ---------------- helpers ----------------
__device__ __forceinline__ float block_reduce_sum(float v, float* sb) {
#pragma unroll
    for (int o = 32; o > 0; o >>= 1) v += __shfl_down(v, o, 64);
    int wid = threadIdx.x >> 6;
    __syncthreads();
    if ((threadIdx.x & 63) == 0) sb[wid] = v;
    __syncthreads();
    return sb[0] + sb[1] + sb[2] + sb[3];
}

// fp32 -> bf16 (RNE)
__device__ __forceinline__ unsigned short f2bf(float x) {
    unsigned u = __float_as_uint(x);
    unsigned r = u + 0x7fff + ((u >> 16) & 1);
    return (unsigned short)(r >> 16);
}

// ---------------- elementwise / setup ----------------
__global__ __launch_bounds__(256) void zero_f(float* p, int n) {
    int i = blockIdx.x * 256 + threadIdx.x;
    if (i < n) p[i] = 0.f;
}

__global__ __launch_bounds__(256) void zero_i(int* p, int n) {
    int i = blockIdx.x * 256 + threadIdx.x;
    if (i < n) p[i] = 0;
}

__global__ __launch_bounds__(256) void x1_kernel(const float* __restrict__ x,
                                                 const float* __restrict__ p_feat,
                                                 const float* __restrict__ p_shared,
                                                 float* __restrict__ x1) {
    int i = blockIdx.x * 256 + threadIdx.x;
    if (i >= NN_NODES * D_IN) return;
    int c = i & (D_IN - 1);
    float v = x[i] * p_feat[c];
    v = fmaxf(v, 0.0f) * p_shared[c];
    x1[i] = v;
}

// dinv[i] = rsqrt(1 + indegree[i])
__global__ __launch_bounds__(256) void to_dinv(const int* __restrict__ cnt, float* __restrict__ dinv) {
    int i = blockIdx.x * 256 + threadIdx.x;
    if (i < NN_NODES) dinv[i] = rsqrtf(1.0f + (float)cnt[i]);
}

// ---------------- input-graph CSR (keyed by dst) ----------------
__global__ __launch_bounds__(256) void ecount_kernel(const int* __restrict__ dst, int* __restrict__ cnt, int E) {
    int e = blockIdx.x * 256 + threadIdx.x;
    if (e < E) atomicAdd(&cnt[dst[e]], 1);
}

__global__ __launch_bounds__(256) void efill_kernel(const int* __restrict__ src, const int* __restrict__ dst,
                                                    const int* __restrict__ ptr, int* __restrict__ cnt,
                                                    int* __restrict__ esrt, int E) {
    int e = blockIdx.x * 256 + threadIdx.x;
    if (e >= E) return;
    int d = dst[e];
    int p = ptr[d] + atomicAdd(&cnt[d], 1);
    esrt[p] = src[e];
}

// out[n][c] = act( dinv[n]^2*h[n][c] + sum_{edges s->n} dinv[s]*dinv[n]*h[s][c] + bias[c] )
__global__ void prop_gather(float* __restrict__ out, const float* __restrict__ h,
                            const float* __restrict__ dinv, const int* __restrict__ eptr,
                            const int* __restrict__ esrt, const float* __restrict__ bias,
                            int C, int act) {
    int n = blockIdx.x, t = threadIdx.x;
    float dn = dinv[n];
    float acc = dn * dn * h[(size_t)n * C + t];
    int p1 = eptr[n + 1];
    for (int p = eptr[n]; p < p1; ++p) {
        int s = esrt[p];
        acc += dinv[s] * dn * h[(size_t)s * C + t];
    }
    if (bias) acc += bias[t];
    if (act == 1) acc = fmaxf(acc, 0.f);
    else if (act == 2) acc = acc > 0.f ? acc : expm1f(acc);
    out[(size_t)n * C + t] = acc;
}

// h = concat(x1, agg)*p_balance; hn = h/(||h||+eps) -> bf16
__global__ __launch_bounds__(256) void h_hn_kernel(const float* __restrict__ x1,
                                                   const float* __restrict__ agg,
                                                   const float* __restrict__ p_balance,
                                                   unsigned short* __restrict__ hn_bf) {
    __shared__ float sb[4];
    int n = blockIdx.x, t = threadIdx.x;
    float v;
    if (t < D_IN) v = x1[(size_t)n * D_IN + t] * p_balance[t];
    else v = agg[(size_t)n * D_IN + (t - D_IN)] * p_balance[t];
    float ss = block_reduce_sum(v * v, sb);
    float inv = 1.0f / (sqrtf(ss) + EPSV);
    hn_bf[(size_t)n * D_H + t] = f2bf(v * inv);
}

// row normalize Z (C=256) -> bf16 (Z unchanged)
__global__ __launch_bounds__(256) void rownorm_kernel(const float* __restrict__ Z,
                                                      unsigned short* __restrict__ zbf) {
    __shared__ float sb[4];
    int n = blockIdx.x, t = threadIdx.x;
    float v = Z[(size_t)n * D_H + t];
    float ss = block_reduce_sum(v * v, sb);
    float inv = 1.0f / (sqrtf(ss) + EPSV);
    zbf[(size_t)n * D_H + t] = f2bf(v * inv);
}

// ---------------- fp32 GEMM (small NN cases) ----------------
#define BM 64
#define BN 64
#define BK 16

__global__ __launch_bounds__(256) void gemm_nn_kernel(const float* __restrict__ A,
                                                      const float* __restrict__ B,
                                                      float* __restrict__ C, int M, int Nn,
                                                      int Kk, const float* __restrict__ bias,
                                                      int ep) {
    __shared__ float As[BK][BM + 4];
    __shared__ float Bs[BK][BN + 4];
    const int tid = threadIdx.x;
    const int tx = tid & 15, ty = tid >> 4;
    const int m0 = blockIdx.y * BM, n0 = blockIdx.x * BN;
    const int arow = tid >> 2, acol = (tid & 3) << 2;
    const int brow = tid >> 4, bcol = (tid & 15) << 2;
    float acc[4][4] = {{0.f}};

    for (int k0 = 0; k0 < Kk; k0 += BK) {
        float4 av = *(const float4*)&A[(size_t)(m0 + arow) * Kk + k0 + acol];
        float4 bv = *(const float4*)&B[(size_t)(k0 + brow) * Nn + n0 + bcol];
        As[acol + 0][arow] = av.x;
        As[acol + 1][arow] = av.y;
        As[acol + 2][arow] = av.z;
        As[acol + 3][arow] = av.w;
        *(float4*)&Bs[brow][bcol] = bv;
        __syncthreads();
#pragma unroll
        for (int k = 0; k < BK; ++k) {
            float4 a = *(const float4*)&As[k][ty << 2];
            float4 b = *(const float4*)&Bs[k][tx << 2];
            acc[0][0] += a.x * b.x; acc[0][1] += a.x * b.y; acc[0][2] += a.x * b.z; acc[0][3] += a.x * b.w;
            acc[1][0] += a.y * b.x; acc[1][1] += a.y * b.y; acc[1][2] += a.y * b.z; acc[1][3] += a.y * b.w;
            acc[2][0] += a.z * b.x; acc[2][1] += a.z * b.y; acc[2][2] += a.z * b.z; acc[2][3] += a.z * b.w;
            acc[3][0] += a.w * b.x; acc[3][1] += a.w * b.y; acc[3][2] += a.w * b.z; acc[3][3] += a.w * b.w;
        }
        __syncthreads();
    }
    float bb[4] = {0.f, 0.f, 0.f, 0.f};
    if (ep) {
#pragma unroll
        for (int j = 0; j < 4; ++j) bb[j] = bias[n0 + (tx << 2) + j];
    }
#pragma unroll
    for (int i = 0; i < 4; ++i) {
        int m = m0 + (ty << 2) + i;
        float r[4];
#pragma unroll
        for (int j = 0; j < 4; ++j) {
            float v = acc[i][j] + bb[j];
            if (ep == 1) v = fmaxf(v, 0.0f);
            else if (ep == 2) v = v > 0.0f ? v : expm1f(v);
            r[j] = v;
        }
        *(float4*)&C[(size_t)m * Nn + n0 + (tx << 2)] = *(float4*)r;
    }
}

// ---------------- MFMA NT GEMM: C[4096,4096] = X @ Y^T, K=256, single bf16 ----------------
// If zrow != nullptr, also accumulates row sums of exp(INV_TEMP * C) into zrow.
__global__ __launch_bounds__(256) void gemm_nt_mfma(const unsigned short* __restrict__ Abf,
                                                    const unsigned short* __restrict__ Bbf,
                                                    float* __restrict__ C,
                                                    float* __restrict__ zrow) {
    __shared__ unsigned short lds[2 * 16 * 512];  // 32 KB
    const int tid = threadIdx.x;
    const int w = tid >> 6, lane = tid & 63;
    const int m0 = blockIdx.y * 128, n0 = blockIdx.x * 128;
    const int wmt = (w >> 1) * 4;
    const int wnt = (w & 1) * 4;

    f32x4 acc[4][4];
#pragma unroll
    for (int i = 0; i < 4; ++i)
#pragma unroll
        for (int j = 0; j < 4; ++j) acc[i][j] = (f32x4)(0.f);

    unsigned short* Ah = lds;
    unsigned short* Bh = lds + 8192;

    const unsigned short* srcs[2] = {Abf, Bbf};
    unsigned short* dsts[2] = {Ah, Bh};

    const int lrow = lane & 15, lquad = lane >> 4;

    for (int k0 = 0; k0 < 256; k0 += 64) {
#pragma unroll
        for (int arr = 0; arr < 2; ++arr) {
            const unsigned short* src = srcs[arr];
            unsigned short* dst = dsts[arr];
            const int base0 = (arr == 0) ? m0 : n0;
#pragma unroll
            for (int ti = 0; ti < 4; ++ti) {
                int t = w + ti * 4;
                int row = base0 + (t & 7) * 16 + lrow;
                int kk = k0 + (t >> 3) * 32 + lquad * 8;
                uint4 v = *(const uint4*)&src[(size_t)row * 256 + kk];
                *(uint4*)&dst[t * 512 + lane * 8] = v;
            }
        }
        __syncthreads();
#pragma unroll
        for (int ksub = 0; ksub < 2; ++ksub) {
            bf16x8 a[4], b[4];
#pragma unroll
            for (int i = 0; i < 4; ++i) {
                a[i] = __builtin_bit_cast(bf16x8, *(const uint4*)&Ah[(ksub * 8 + wmt + i) * 512 + lane * 8]);
                b[i] = __builtin_bit_cast(bf16x8, *(const uint4*)&Bh[(ksub * 8 + wnt + i) * 512 + lane * 8]);
            }
#pragma unroll
            for (int i = 0; i < 4; ++i)
#pragma unroll
                for (int j = 0; j < 4; ++j)
                    acc[i][j] = __builtin_amdgcn_mfma_f32_16x16x32_bf16(a[i], b[j], acc[i][j], 0, 0, 0);
        }
        __syncthreads();
    }
    const int col = lane & 15, rq = (lane >> 4) * 4;
#pragma unroll
    for (int i = 0; i < 4; ++i) {
        int rb = m0 + (wmt + i) * 16 + rq;
#pragma unroll
        for (int j = 0; j < 4; ++j) {
            int cb = n0 + (wnt + j) * 16 + col;
#pragma unroll
            for (int r = 0; r < 4; ++r)
                C[(size_t)(rb + r) * NN_NODES + cb] = acc[i][j][r];
        }
    }
    if (zrow) {
#pragma unroll
        for (int i = 0; i < 4; ++i) {
            int rb = m0 + (wmt + i) * 16 + rq;
#pragma unroll
            for (int r = 0; r < 4; ++r) {
                float s = 0.f;
#pragma unroll
                for (int j = 0; j < 4; ++j) s += __expf(INV_TEMP * acc[i][j][r]);
#pragma unroll
                for (int o = 1; o < 16; o <<= 1) s += __shfl_xor(s, o, 64);
                if ((lane & 15) == 0) atomicAdd(&zrow[rb + r], s);
            }
        }
    }
}

// ---------------- top-k: cached per-thread candidate (round-9 version) ----------------
__global__ __launch_bounds__(256) void topk_kernel(const float* __restrict__ S,
                                                   float* __restrict__ vals,
                                                   int* __restrict__ idxo) {
    __shared__ float wvs[8];
    __shared__ int wis[8];
    const int i = blockIdx.x, t = threadIdx.x;
    const int lane = t & 63, wid = t >> 6;
    const float* row = &S[(size_t)i * NN_NODES];
    float v[16];
    int id[16];
#pragma unroll
    for (int u = 0; u < 4; ++u) {
        int base = u * 1024 + t * 4;
        float4 f = *(const float4*)&row[base];
        v[u * 4 + 0] = f.x; id[u * 4 + 0] = base + 0;
        v[u * 4 + 1] = f.y; id[u * 4 + 1] = base + 1;
        v[u * 4 + 2] = f.z; id[u * 4 + 2] = base + 2;
        v[u * 4 + 3] = f.w; id[u * 4 + 3] = base + 3;
    }
    float bv = v[0];
    int bi = id[0];
#pragma unroll
    for (int u = 1; u < 16; ++u)
        if (v[u] > bv || (v[u] == bv && id[u] < bi)) { bv = v[u]; bi = id[u]; }

    for (int k = 0; k < KTOP; ++k) {
        float mv = bv;
        int mi = bi;
#pragma unroll
        for (int o = 1; o < 64; o <<= 1) {
            float ov = __shfl_xor(mv, o, 64);
            int oi = __shfl_xor(mi, o, 64);
            if (ov > mv || (ov == mv && oi < mi)) { mv = ov; mi = oi; }
        }
        int slot = ((k & 1) << 2) + wid;
        if (lane == 0) { wvs[slot] = mv; wis[slot] = mi; }
        __syncthreads();
        int b0 = (k & 1) << 2;
        mv = wvs[b0]; mi = wis[b0];
#pragma unroll
        for (int ww = 1; ww < 4; ++ww) {
            float ov = wvs[b0 + ww];
            int oi = wis[b0 + ww];
            if (ov > mv || (ov == mv && oi < mi)) { mv = ov; mi = oi; }
        }
        if (t == 0) {
            vals[i * KTOP + k] = isnan(mv) ? 0.f : mv;
            idxo[i * KTOP + k] = mi;
        }
        if (bi == mi) {
#pragma unroll
            for (int u = 0; u < 16; ++u)
                if (id[u] == mi) v[u] = -INFINITY;
            bv = v[0]; bi = id[0];
#pragma unroll
            for (int u = 1; u < 16; ++u)
                if (v[u] > bv || (v[u] == bv && id[u] < bi)) { bv = v[u]; bi = id[u]; }
        }
    }
}

// ---------------- sparse W construction ----------------
__global__ __launch_bounds__(256) void count_indeg(const int* __restrict__ idx, int* __restrict__ cnt) {
    int e = blockIdx.x * 256 + threadIdx.x;
    if (e < NEDGE) atomicAdd(&cnt[idx[e]], 1);
}

// exclusive scan of 4096 counts -> ptr[4097]; zeroes cnt after reading.
__global__ __launch_bounds__(256) void scan_kernel(int* __restrict__ cnt, int* __restrict__ ptr) {
    __shared__ int tmp[256];
    int t = threadIdx.x;
    int base = t * 16;
    int local[16]; int s = 0;
#pragma unroll
    for (int u = 0; u < 16; ++u) { local[u] = s; s += cnt[base + u]; }
#pragma unroll
    for (int u = 0; u < 16; ++u) cnt[base + u] = 0;
    tmp[t] = s;
    __syncthreads();
    for (int off = 1; off < 256; off <<= 1) {
        int v = (t >= off) ? tmp[t - off] : 0;
        __syncthreads();
        tmp[t] += v;
        __syncthreads();
    }
    int prefix = (t > 0) ? tmp[t - 1] : 0;
#pragma unroll
    for (int u = 0; u < 16; ++u) ptr[base + u] = prefix + local[u];
    if (t == 255) ptr[NN_NODES] = prefix + s;
}

__global__ __launch_bounds__(256) void fill_rev(const int* __restrict__ idx, const float* __restrict__ vals,
                                                const int* __restrict__ ptr, int* __restrict__ fcnt,
                                                int* __restrict__ rrow, int* __restrict__ rsrc,
                                                float* __restrict__ rval) {
    int e = blockIdx.x * 256 + threadIdx.x;
    if (e >= NEDGE) return;
    int i = e / KTOP;
    int j = idx[e];
    int p = ptr[j] + atomicAdd(&fcnt[j], 1);
    rrow[p] = j; rsrc[p] = i; rval[p] = vals[e];
}

// fused fwd+rev edge weights (grid covers 2*NEDGE)
__global__ __launch_bounds__(256) void wedges_kernel(const int* __restrict__ idx, const float* __restrict__ vals,
                                                     const int* __restrict__ rrow, const int* __restrict__ rsrc,
                                                     const float* __restrict__ rval,
                                                     float* __restrict__ wfwd, float* __restrict__ wrev) {
    int e = blockIdx.x * 256 + threadIdx.x;
    if (e < NEDGE) {
        int i = e / KTOP;
        int j = idx[e];
        float a = vals[e];
        float c = 1.0f;
        const int* lj = &idx[j * KTOP];
#pragma unroll
        for (int k = 0; k < KTOP; ++k)
            if (lj[k] == i) { a += vals[j * KTOP + k]; c = 2.0f; }
        float w = a / c;
        wfwd[e] = w > 0.f ? w : 0.f;
    } else if (e < 2 * NEDGE) {
        int e2 = e - NEDGE;
        int i = rrow[e2], s = rsrc[e2];
        const int* li = &idx[i * KTOP];
        bool dup = false;
#pragma unroll
        for (int k = 0; k < KTOP; ++k)
            if (li[k] == s) dup = true;
        wrev[e2] = dup ? 0.f : fmaxf(rval[e2], 0.f);
    }
}

// out[i,:] = act(sum_j W[i,j]*X[j,:] + bias)
__global__ __launch_bounds__(256) void spmm_kernel(float* __restrict__ out, const float* __restrict__ X,
                                                   const int* __restrict__ idx, const float* __restrict__ wfwd,
                                                   const int* __restrict__ ptr, const int* __restrict__ rsrc,
                                                   const float* __restrict__ wrev,
                                                   const float* __restrict__ bias, int act) {
    int i = blockIdx.x, c = threadIdx.x;
    float acc = 0.f;
#pragma unroll
    for (int k = 0; k < KTOP; ++k) {
        int j = idx[i * KTOP + k];
        float w = wfwd[i * KTOP + k];
        acc += w * X[(size_t)j * D_H + c];
    }
    int p1 = ptr[i + 1];
    for (int p = ptr[i]; p < p1; ++p) {
        float w = wrev[p];
        if (w != 0.f) acc += w * X[(size_t)rsrc[p] * D_H + c];
    }
    acc += bias[c];
    if (act == 1) acc = fmaxf(acc, 0.f);
    else acc = acc > 0.f ? acc : expm1f(acc);
    out[(size_t)i * D_H + c] = acc;
}

// fused pf/pb over fwd+rev lists; prob = exp(5 s)/zrow
__global__ __launch_bounds__(256) void pfpb_edges(const float* __restrict__ S,
                                                  const int* __restrict__ idx,
                                                  const float* __restrict__ wfwd,
                                                  const int* __restrict__ rrow,
                                                  const int* __restrict__ rsrc,
                                                  const float* __restrict__ wrev,
                                                  const float* __restrict__ zrow,
                                                  float* __restrict__ pf, float* __restrict__ pb) {
    int e = blockIdx.x * 256 + threadIdx.x;
    if (e >= 2 * NEDGE) return;
    int i, j;
    float wv;
    if (e < NEDGE) { i = e / KTOP; j = idx[e]; wv = wfwd[e]; }
    else { int e2 = e - NEDGE; i = rrow[e2]; j = rsrc[e2]; wv = wrev[e2]; }
    if (wv == 0.f) return;
    float sf = S[(size_t)i * NN_NODES + j];
    float sbk = S[(size_t)j * NN_NODES + i];
    float pfv = expf(sf * INV_TEMP) / zrow[i] * wv;
    float pbv = expf(sbk * INV_TEMP) / zrow[j] * wv;
    atomicAdd(&pf[i], pfv);
    atomicAdd(&pb[i], pbv);
}

__global__ __launch_bounds__(256) void loss_kernel(const float* __restrict__ S,
                                                   const float* __restrict__ zrow,
                                                   const float* __restrict__ pf,
                                                   const float* __restrict__ pb,
                                                   float* __restrict__ out) {
    __shared__ float sb[4];
    int t = threadIdx.x;
    float s = 0.f;
    for (int i = t; i < NN_NODES; i += 256) {
        float p = expf(INV_TEMP * S[(size_t)i * NN_NODES + i]) / zrow[i];
        s += -logf(fmaxf(p, EPSV));
        s += 0.5f * (-logf(fmaxf(pf[i], EPSV)) - logf(fmaxf(pb[i], EPSV)));
    }
    float tot = block_reduce_sum(s, sb);
    if (t == 0) out[0] = tot / (float)NN_NODES;
}

// ---------------- launch ----------------
extern "C" void kernel_launch(void* const* d_in, const int* in_sizes, int n_in,
                              void* d_out, int out_size, void* d_ws, size_t ws_size,
                              hipStream_t stream) {
    (void)n_in; (void)out_size; (void)ws_size;
    const float* x = (const float*)d_in[0];
    const int* esrc = (const int*)d_in[1];
    const int* edst = (const int*)d_in[2];
    const float* p_feat = (const float*)d_in[3];
    const float* p_shared = (const float*)d_in[4];
    const float* p_balance = (const float*)d_in[5];
    const float* W1 = (const float*)d_in[6];
    const float* b1 = (const float*)d_in[7];
    const float* W2 = (const float*)d_in[8];
    const float* b2 = (const float*)d_in[9];
    const int E = in_sizes[1];

    float* ws = (float*)d_ws;
    size_t off = 0;
    float* SIM = ws + off; off += (size_t)NN_NODES * NN_NODES;
    float* X1  = ws + off; off += (size_t)NN_NODES * D_IN;
    float* AGG = ws + off; off += (size_t)NN_NODES * D_IN;
    float* T1  = ws + off; off += (size_t)NN_NODES * D_H;
    float* H1  = ws + off; off += (size_t)NN_NODES * D_H;
    float* T2  = ws + off; off += (size_t)NN_NODES * D_H;
    float* Z1  = ws + off; off += (size_t)NN_NODES * D_H;
    float* G1  = ws + off; off += (size_t)NN_NODES * D_H;
    float* Z2  = ws + off; off += (size_t)NN_NODES * D_H;
    float* DINV = ws + off; off += NN_NODES;
    float* VALS = ws + off; off += (size_t)NEDGE;
    int*   IDX  = (int*)(ws + off); off += (size_t)NEDGE;
    float* WFWD = ws + off; off += (size_t)NEDGE;
    int*   RPTR = (int*)(ws + off); off += NN_NODES + 1;
    int*   FCNT = (int*)(ws + off); off += NN_NODES;
    int*   RROW = (int*)(ws + off); off += (size_t)NEDGE;
    int*   RSRC = (int*)(ws + off); off += (size_t)NEDGE;
    float* RVAL = ws + off; off += (size_t)NEDGE;
    float* WREV = ws + off; off += (size_t)NEDGE;
    float* ZROW = ws + off; off += NN_NODES;   // ZROW,PF,PB contiguous (zeroed together)
    float* PF = ws + off; off += NN_NODES;
    float* PB = ws + off; off += NN_NODES;
    unsigned short* HNbf = (unsigned short*)(ws + off); off += (size_t)NN_NODES * D_H / 2;
    unsigned short* Z1bf = (unsigned short*)(ws + off); off += (size_t)NN_NODES * D_H / 2;
    unsigned short* Z2bf = (unsigned short*)(ws + off); off += (size_t)NN_NODES * D_H / 2;
    int* ECNT = (int*)(ws + off); off += NN_NODES;
    int* EPTR = (int*)(ws + off); off += NN_NODES + 1;
    int* ESRT = (int*)(ws + off); off += (size_t)E;

    const int EB = (NEDGE + 255) / 256;
    const int NB = (NN_NODES + 255) / 256;
    const int EBi = (E + 255) / 256;

    // 1. x1
    x1_kernel<<<(NN_NODES * D_IN + 255) / 256, 256, 0, stream>>>(x, p_feat, p_shared, X1);
    // 2. input-graph CSR + dinv (deg = 1 + indegree)
    zero_i<<<NB, 256, 0, stream>>>(ECNT, NN_NODES);
    ecount_kernel<<<EBi, 256, 0, stream>>>(edst, ECNT, E);
    to_dinv<<<NB, 256, 0, stream>>>(ECNT, DINV);
    scan_kernel<<<1, 256, 0, stream>>>(ECNT, EPTR);  // zeroes ECNT for efill
    efill_kernel<<<EBi, 256, 0, stream>>>(esrc, edst, EPTR, ECNT, ESRT, E);
    // zero ZROW/PF/PB (contiguous)
    zero_f<<<(3 * NN_NODES + 255) / 256, 256, 0, stream>>>(ZROW, 3 * NN_NODES);
    // 3. agg = A_norm @ x1  (gather)
    prop_gather<<<NN_NODES, D_IN, 0, stream>>>(AGG, X1, DINV, EPTR, ESRT, nullptr, D_IN, 0);
    // 4. h, hn (bf16)
    h_hn_kernel<<<NN_NODES, 256, 0, stream>>>(X1, AGG, p_balance, HNbf);
    // 5. sim = hn @ hn^T  (MFMA bf16)
    {
        dim3 g(NN_NODES / 128, NN_NODES / 128);
        gemm_nt_mfma<<<g, 256, 0, stream>>>(HNbf, HNbf, SIM, nullptr);
    }
    // 6. topk
    topk_kernel<<<NN_NODES, 256, 0, stream>>>(SIM, VALS, IDX);
    // 7. sparse W: reverse CSR + fused edge weights
    zero_i<<<NB, 256, 0, stream>>>(FCNT, NN_NODES);
    count_indeg<<<EB, 256, 0, stream>>>(IDX, FCNT);
    scan_kernel<<<1, 256, 0, stream>>>(FCNT, RPTR);  // zeroes FCNT for fill_rev
    fill_rev<<<EB, 256, 0, stream>>>(IDX, VALS, RPTR, FCNT, RROW, RSRC, RVAL);
    wedges_kernel<<<2 * EB, 256, 0, stream>>>(IDX, VALS, RROW, RSRC, RVAL, WFWD, WREV);
    // 8. t1 = x1 @ W1
    {
        dim3 g(D_H / BN, NN_NODES / BM);
        gemm_nn_kernel<<<g, 256, 0, stream>>>(X1, W1, T1, NN_NODES, D_H, D_IN, nullptr, 0);
    }
    // 9. h1 = relu(prop(t1) + b1)
    prop_gather<<<NN_NODES, D_H, 0, stream>>>(H1, T1, DINV, EPTR, ESRT, b1, D_H, 1);
    // 10. z1 = elu(prop(h1@W2) + b2)
    {
        dim3 g(D_H / BN, NN_NODES / BM);
        gemm_nn_kernel<<<g, 256, 0, stream>>>(H1, W2, T2, NN_NODES, D_H, D_H, nullptr, 0);
    }
    prop_gather<<<NN_NODES, D_H, 0, stream>>>(Z1, T2, DINV, EPTR, ESRT, b2, D_H, 2);
    // 11. g1 = relu(W @ t1 + b1)   [sparse]
    spmm_kernel<<<NN_NODES, 256, 0, stream>>>(G1, T1, IDX, WFWD, RPTR, RSRC, WREV, b1, 1);
    // 12. g2 = g1 @ W2 (into T2)
    {
        dim3 g(D_H / BN, NN_NODES / BM);
        gemm_nn_kernel<<<g, 256, 0, stream>>>(G1, W2, T2, NN_NODES, D_H, D_H, nullptr, 0);
    }
    // 13. z2 = elu(W @ g2 + b2)   [sparse]
    spmm_kernel<<<NN_NODES, 256, 0, stream>>>(Z2, T2, IDX, WFWD, RPTR, RSRC, WREV, b2, 2);
    // 14. normalize z1, z2 -> bf16
    rownorm_kernel<<<NN_NODES, 256, 0, stream>>>(Z1, Z1bf);
    rownorm_kernel<<<NN_NODES, 256, 0, stream>>>(Z2, Z2bf);
    // 15. S = z1n @ z2n^T (MFMA bf16) with fused exp row-sum -> ZROW
    {
        dim3 g(NN_NODES / 128, NN_NODES / 128);
        gemm_nt_mfma<<<g, 256, 0, stream>>>(Z1bf, Z2bf, SIM, ZROW);
    }
    // 16. pf / pb (fused fwd+rev)
    pfpb_edges<<<2 * EB, 256, 0, stream>>>(SIM, IDX, WFWD, RROW, RSRC, WREV, ZROW, PF, PB);
    // 17. loss
    loss_kernel<<<1, 256, 0, stream>>>(SIM, ZROW, PF, PB, (float*)d_out);
}

// Round 11
// 477.150 us; speedup vs baseline: 1.2117x; 1.0159x over previous
//
#include <hip/hip_runtime.h>
#include <math.h>

#define NN_NODES 4096
#define D_IN 128
#define D_H 256
#define KTOP 17
#define NEDGE (NN_NODES * KTOP)
#define INV_TEMP 5.0f
#define EPSV 1e-8f
#define CCAP 1024

typedef __bf16 bf16x8 __attribute__((ext_vector_type(8)));
typedef float f32x4 __attribute__((ext_vector_type(4)));

// ---------------- helpers ----------------
__device__ __forceinline__ float block_reduce_sum(float v, float* sb) {
#pragma unroll
    for (int o = 32; o > 0; o >>= 1) v += __shfl_down(v, o, 64);
    int wid = threadIdx.x >> 6;
    __syncthreads();
    if ((threadIdx.x & 63) == 0) sb[wid] = v;
    __syncthreads();
    return sb[0] + sb[1] + sb[2] + sb[3];
}

// fp32 -> bf16 (RNE)
__device__ __forceinline__ unsigned short f2bf(float x) {
    unsigned u = __float_as_uint(x);
    unsigned r = u + 0x7fff + ((u >> 16) & 1);
    return (unsigned short)(r >> 16);
}

// ---------------- elementwise / setup ----------------
__global__ __launch_bounds__(256) void zero_f(float* p, int n) {
    int i = blockIdx.x * 256 + threadIdx.x;
    if (i < n) p[i] = 0.f;
}

__global__ __launch_bounds__(256) void zero_i(int* p, int n) {
    int i = blockIdx.x * 256 + threadIdx.x;
    if (i < n) p[i] = 0;
}

__global__ __launch_bounds__(256) void x1_kernel(const float* __restrict__ x,
                                                 const float* __restrict__ p_feat,
                                                 const float* __restrict__ p_shared,
                                                 float* __restrict__ x1) {
    int i = blockIdx.x * 256 + threadIdx.x;
    if (i >= NN_NODES * D_IN) return;
    int c = i & (D_IN - 1);
    float v = x[i] * p_feat[c];
    v = fmaxf(v, 0.0f) * p_shared[c];
    x1[i] = v;
}

// dinv[i] = rsqrt(1 + indegree[i])
__global__ __launch_bounds__(256) void to_dinv(const int* __restrict__ cnt, float* __restrict__ dinv) {
    int i = blockIdx.x * 256 + threadIdx.x;
    if (i < NN_NODES) dinv[i] = rsqrtf(1.0f + (float)cnt[i]);
}

// ---------------- input-graph CSR (keyed by dst) ----------------
__global__ __launch_bounds__(256) void ecount_kernel(const int* __restrict__ dst, int* __restrict__ cnt, int E) {
    int e = blockIdx.x * 256 + threadIdx.x;
    if (e < E) atomicAdd(&cnt[dst[e]], 1);
}

__global__ __launch_bounds__(256) void efill_kernel(const int* __restrict__ src, const int* __restrict__ dst,
                                                    const int* __restrict__ ptr, int* __restrict__ cnt,
                                                    int* __restrict__ esrt, int E) {
    int e = blockIdx.x * 256 + threadIdx.x;
    if (e >= E) return;
    int d = dst[e];
    int p = ptr[d] + atomicAdd(&cnt[d], 1);
    esrt[p] = src[e];
}

// out[n][c] = act( dinv[n]^2*h[n][c] + sum_{edges s->n} dinv[s]*dinv[n]*h[s][c] + bias[c] )
__global__ void prop_gather(float* __restrict__ out, const float* __restrict__ h,
                            const float* __restrict__ dinv, const int* __restrict__ eptr,
                            const int* __restrict__ esrt, const float* __restrict__ bias,
                            int C, int act) {
    int n = blockIdx.x, t = threadIdx.x;
    float dn = dinv[n];
    float acc = dn * dn * h[(size_t)n * C + t];
    int p1 = eptr[n + 1];
    for (int p = eptr[n]; p < p1; ++p) {
        int s = esrt[p];
        acc += dinv[s] * dn * h[(size_t)s * C + t];
    }
    if (bias) acc += bias[t];
    if (act == 1) acc = fmaxf(acc, 0.f);
    else if (act == 2) acc = acc > 0.f ? acc : expm1f(acc);
    out[(size_t)n * C + t] = acc;
}

// h = concat(x1, agg)*p_balance; hn = h/(||h||+eps) -> bf16
__global__ __launch_bounds__(256) void h_hn_kernel(const float* __restrict__ x1,
                                                   const float* __restrict__ agg,
                                                   const float* __restrict__ p_balance,
                                                   unsigned short* __restrict__ hn_bf) {
    __shared__ float sb[4];
    int n = blockIdx.x, t = threadIdx.x;
    float v;
    if (t < D_IN) v = x1[(size_t)n * D_IN + t] * p_balance[t];
    else v = agg[(size_t)n * D_IN + (t - D_IN)] * p_balance[t];
    float ss = block_reduce_sum(v * v, sb);
    float inv = 1.0f / (sqrtf(ss) + EPSV);
    hn_bf[(size_t)n * D_H + t] = f2bf(v * inv);
}

// row normalize two Z buffers -> bf16 in one launch (grid 2*NN_NODES)
__global__ __launch_bounds__(256) void rownorm2_kernel(const float* __restrict__ Z1,
                                                       unsigned short* __restrict__ z1bf,
                                                       const float* __restrict__ Z2,
                                                       unsigned short* __restrict__ z2bf) {
    __shared__ float sb[4];
    int b = blockIdx.x, t = threadIdx.x;
    const float* Z = (b < NN_NODES) ? Z1 : Z2;
    unsigned short* zbf = (b < NN_NODES) ? z1bf : z2bf;
    int n = (b < NN_NODES) ? b : b - NN_NODES;
    float v = Z[(size_t)n * D_H + t];
    float ss = block_reduce_sum(v * v, sb);
    float inv = 1.0f / (sqrtf(ss) + EPSV);
    zbf[(size_t)n * D_H + t] = f2bf(v * inv);
}

// ---------------- fp32 GEMM (small NN cases) ----------------
#define BM 64
#define BN 64
#define BK 16

__global__ __launch_bounds__(256) void gemm_nn_kernel(const float* __restrict__ A,
                                                      const float* __restrict__ B,
                                                      float* __restrict__ C, int M, int Nn,
                                                      int Kk, const float* __restrict__ bias,
                                                      int ep) {
    __shared__ float As[BK][BM + 4];
    __shared__ float Bs[BK][BN + 4];
    const int tid = threadIdx.x;
    const int tx = tid & 15, ty = tid >> 4;
    const int m0 = blockIdx.y * BM, n0 = blockIdx.x * BN;
    const int arow = tid >> 2, acol = (tid & 3) << 2;
    const int brow = tid >> 4, bcol = (tid & 15) << 2;
    float acc[4][4] = {{0.f}};

    for (int k0 = 0; k0 < Kk; k0 += BK) {
        float4 av = *(const float4*)&A[(size_t)(m0 + arow) * Kk + k0 + acol];
        float4 bv = *(const float4*)&B[(size_t)(k0 + brow) * Nn + n0 + bcol];
        As[acol + 0][arow] = av.x;
        As[acol + 1][arow] = av.y;
        As[acol + 2][arow] = av.z;
        As[acol + 3][arow] = av.w;
        *(float4*)&Bs[brow][bcol] = bv;
        __syncthreads();
#pragma unroll
        for (int k = 0; k < BK; ++k) {
            float4 a = *(const float4*)&As[k][ty << 2];
            float4 b = *(const float4*)&Bs[k][tx << 2];
            acc[0][0] += a.x * b.x; acc[0][1] += a.x * b.y; acc[0][2] += a.x * b.z; acc[0][3] += a.x * b.w;
            acc[1][0] += a.y * b.x; acc[1][1] += a.y * b.y; acc[1][2] += a.y * b.z; acc[1][3] += a.y * b.w;
            acc[2][0] += a.z * b.x; acc[2][1] += a.z * b.y; acc[2][2] += a.z * b.z; acc[2][3] += a.z * b.w;
            acc[3][0] += a.w * b.x; acc[3][1] += a.w * b.y; acc[3][2] += a.w * b.z; acc[3][3] += a.w * b.w;
        }
        __syncthreads();
    }
    float bb[4] = {0.f, 0.f, 0.f, 0.f};
    if (ep) {
#pragma unroll
        for (int j = 0; j < 4; ++j) bb[j] = bias[n0 + (tx << 2) + j];
    }
#pragma unroll
    for (int i = 0; i < 4; ++i) {
        int m = m0 + (ty << 2) + i;
        float r[4];
#pragma unroll
        for (int j = 0; j < 4; ++j) {
            float v = acc[i][j] + bb[j];
            if (ep == 1) v = fmaxf(v, 0.0f);
            else if (ep == 2) v = v > 0.0f ? v : expm1f(v);
            r[j] = v;
        }
        *(float4*)&C[(size_t)m * Nn + n0 + (tx << 2)] = *(float4*)r;
    }
}

// ---------------- MFMA NT GEMM: C[4096,4096] = X @ Y^T, K=256, single bf16 ----------------
__global__ __launch_bounds__(256) void gemm_nt_mfma(const unsigned short* __restrict__ Abf,
                                                    const unsigned short* __restrict__ Bbf,
                                                    float* __restrict__ C,
                                                    float* __restrict__ zrow) {
    __shared__ unsigned short lds[2 * 16 * 512];  // 32 KB
    const int tid = threadIdx.x;
    const int w = tid >> 6, lane = tid & 63;
    const int m0 = blockIdx.y * 128, n0 = blockIdx.x * 128;
    const int wmt = (w >> 1) * 4;
    const int wnt = (w & 1) * 4;

    f32x4 acc[4][4];
#pragma unroll
    for (int i = 0; i < 4; ++i)
#pragma unroll
        for (int j = 0; j < 4; ++j) acc[i][j] = (f32x4)(0.f);

    unsigned short* Ah = lds;
    unsigned short* Bh = lds + 8192;

    const unsigned short* srcs[2] = {Abf, Bbf};
    unsigned short* dsts[2] = {Ah, Bh};

    const int lrow = lane & 15, lquad = lane >> 4;

    for (int k0 = 0; k0 < 256; k0 += 64) {
#pragma unroll
        for (int arr = 0; arr < 2; ++arr) {
            const unsigned short* src = srcs[arr];
            unsigned short* dst = dsts[arr];
            const int base0 = (arr == 0) ? m0 : n0;
#pragma unroll
            for (int ti = 0; ti < 4; ++ti) {
                int t = w + ti * 4;
                int row = base0 + (t & 7) * 16 + lrow;
                int kk = k0 + (t >> 3) * 32 + lquad * 8;
                uint4 v = *(const uint4*)&src[(size_t)row * 256 + kk];
                *(uint4*)&dst[t * 512 + lane * 8] = v;
            }
        }
        __syncthreads();
#pragma unroll
        for (int ksub = 0; ksub < 2; ++ksub) {
            bf16x8 a[4], b[4];
#pragma unroll
            for (int i = 0; i < 4; ++i) {
                a[i] = __builtin_bit_cast(bf16x8, *(const uint4*)&Ah[(ksub * 8 + wmt + i) * 512 + lane * 8]);
                b[i] = __builtin_bit_cast(bf16x8, *(const uint4*)&Bh[(ksub * 8 + wnt + i) * 512 + lane * 8]);
            }
#pragma unroll
            for (int i = 0; i < 4; ++i)
#pragma unroll
                for (int j = 0; j < 4; ++j)
                    acc[i][j] = __builtin_amdgcn_mfma_f32_16x16x32_bf16(a[i], b[j], acc[i][j], 0, 0, 0);
        }
        __syncthreads();
    }
    const int col = lane & 15, rq = (lane >> 4) * 4;
#pragma unroll
    for (int i = 0; i < 4; ++i) {
        int rb = m0 + (wmt + i) * 16 + rq;
#pragma unroll
        for (int j = 0; j < 4; ++j) {
            int cb = n0 + (wnt + j) * 16 + col;
#pragma unroll
            for (int r = 0; r < 4; ++r)
                C[(size_t)(rb + r) * NN_NODES + cb] = acc[i][j][r];
        }
    }
    if (zrow) {
#pragma unroll
        for (int i = 0; i < 4; ++i) {
            int rb = m0 + (wmt + i) * 16 + rq;
#pragma unroll
            for (int r = 0; r < 4; ++r) {
                float s = 0.f;
#pragma unroll
                for (int j = 0; j < 4; ++j) s += __expf(INV_TEMP * acc[i][j][r]);
#pragma unroll
                for (int o = 1; o < 16; o <<= 1) s += __shfl_xor(s, o, 64);
                if ((lane & 15) == 0) atomicAdd(&zrow[rb + r], s);
            }
        }
    }
}

// ---------------- top-k: threshold prefilter + small exact selection ----------------
// T = 17th-largest per-thread max => {x >= T} contains >=17 elems and all of top-17.
// Wave 0 extracts exact (value desc, idx asc) top-17 from the candidate list.
// Degenerate mass-tie rows (cnt > CCAP) fall back to full block-wide extraction.
__global__ __launch_bounds__(256) void topk_kernel(const float* __restrict__ S,
                                                   float* __restrict__ vals,
                                                   int* __restrict__ idxo) {
    __shared__ float sm[256];
    __shared__ float tshr;
    __shared__ int ccnt;
    __shared__ float cv[CCAP];
    __shared__ int ci[CCAP];
    __shared__ float wvs[8];
    __shared__ int wis[8];
    const int i = blockIdx.x, t = threadIdx.x;
    const int lane = t & 63, wid = t >> 6;
    const float* row = &S[(size_t)i * NN_NODES];
    float v[16];
    int id[16];
#pragma unroll
    for (int u = 0; u < 4; ++u) {
        int base = u * 1024 + t * 4;
        float4 f = *(const float4*)&row[base];
        v[u * 4 + 0] = f.x; id[u * 4 + 0] = base + 0;
        v[u * 4 + 1] = f.y; id[u * 4 + 1] = base + 1;
        v[u * 4 + 2] = f.z; id[u * 4 + 2] = base + 2;
        v[u * 4 + 3] = f.w; id[u * 4 + 3] = base + 3;
    }
    float m = v[0];
#pragma unroll
    for (int u = 1; u < 16; ++u) m = fmaxf(m, v[u]);
    sm[t] = m;
    if (t == 0) ccnt = 0;
    __syncthreads();

    // wave 0: 17th-largest of 256 maxima (value desc, slot asc)
    if (wid == 0) {
        float a[4];
        int ai[4];
#pragma unroll
        for (int u = 0; u < 4; ++u) { a[u] = sm[u * 64 + lane]; ai[u] = u * 64 + lane; }
        float bv = a[0];
        int bi = ai[0];
#pragma unroll
        for (int u = 1; u < 4; ++u)
            if (a[u] > bv || (a[u] == bv && ai[u] < bi)) { bv = a[u]; bi = ai[u]; }
        float T = bv;
        for (int k = 0; k < KTOP; ++k) {
            float mv = bv;
            int mi = bi;
#pragma unroll
            for (int o = 1; o < 64; o <<= 1) {
                float ov = __shfl_xor(mv, o, 64);
                int oi = __shfl_xor(mi, o, 64);
                if (ov > mv || (ov == mv && oi < mi)) { mv = ov; mi = oi; }
            }
            T = mv;
            if (bi == mi) {
#pragma unroll
                for (int u = 0; u < 4; ++u)
                    if (ai[u] == mi) a[u] = -INFINITY;
                bv = a[0]; bi = ai[0];
#pragma unroll
                for (int u = 1; u < 4; ++u)
                    if (a[u] > bv || (a[u] == bv && ai[u] < bi)) { bv = a[u]; bi = ai[u]; }
            }
        }
        if (lane == 0) tshr = T;
    }
    __syncthreads();
    const float T = tshr;
    // emit candidates >= T
#pragma unroll
    for (int u = 0; u < 16; ++u) {
        if (v[u] >= T) {
            int p = atomicAdd(&ccnt, 1);
            if (p < CCAP) { cv[p] = v[u]; ci[p] = id[u]; }
        }
    }
    __syncthreads();
    const int cnt = ccnt;

    if (cnt <= CCAP) {
        // fast path: wave 0 exact top-17 of cnt candidates
        if (wid == 0) {
            float a[16];
            int ai[16];
#pragma unroll
            for (int u = 0; u < 16; ++u) {
                int p = lane + u * 64;
                if (p < cnt) { a[u] = cv[p]; ai[u] = ci[p]; }
                else { a[u] = -INFINITY; ai[u] = 0x7fffffff; }
            }
            float bv = a[0];
            int bi = ai[0];
#pragma unroll
            for (int u = 1; u < 16; ++u)
                if (a[u] > bv || (a[u] == bv && ai[u] < bi)) { bv = a[u]; bi = ai[u]; }
            for (int k = 0; k < KTOP; ++k) {
                float mv = bv;
                int mi = bi;
#pragma unroll
                for (int o = 1; o < 64; o <<= 1) {
                    float ov = __shfl_xor(mv, o, 64);
                    int oi = __shfl_xor(mi, o, 64);
                    if (ov > mv || (ov == mv && oi < mi)) { mv = ov; mi = oi; }
                }
                if (lane == 0) {
                    vals[i * KTOP + k] = isnan(mv) ? 0.f : mv;
                    idxo[i * KTOP + k] = mi;
                }
                if (bi == mi) {
#pragma unroll
                    for (int u = 0; u < 16; ++u)
                        if (ai[u] == mi) a[u] = -INFINITY;
                    bv = a[0]; bi = ai[0];
#pragma unroll
                    for (int u = 1; u < 16; ++u)
                        if (a[u] > bv || (a[u] == bv && ai[u] < bi)) { bv = a[u]; bi = ai[u]; }
                }
            }
        }
    } else {
        // fallback: full block-wide cached-candidate extraction (registers intact)
        float bv = v[0];
        int bi = id[0];
#pragma unroll
        for (int u = 1; u < 16; ++u)
            if (v[u] > bv || (v[u] == bv && id[u] < bi)) { bv = v[u]; bi = id[u]; }
        for (int k = 0; k < KTOP; ++k) {
            float mv = bv;
            int mi = bi;
#pragma unroll
            for (int o = 1; o < 64; o <<= 1) {
                float ov = __shfl_xor(mv, o, 64);
                int oi = __shfl_xor(mi, o, 64);
                if (ov > mv || (ov == mv && oi < mi)) { mv = ov; mi = oi; }
            }
            int slot = ((k & 1) << 2) + wid;
            if (lane == 0) { wvs[slot] = mv; wis[slot] = mi; }
            __syncthreads();
            int b0 = (k & 1) << 2;
            mv = wvs[b0]; mi = wis[b0];
#pragma unroll
            for (int ww = 1; ww < 4; ++ww) {
                float ov = wvs[b0 + ww];
                int oi = wis[b0 + ww];
                if (ov > mv || (ov == mv && oi < mi)) { mv = ov; mi = oi; }
            }
            if (t == 0) {
                vals[i * KTOP + k] = isnan(mv) ? 0.f : mv;
                idxo[i * KTOP + k] = mi;
            }
            if (bi == mi) {
#pragma unroll
                for (int u = 0; u < 16; ++u)
                    if (id[u] == mi) v[u] = -INFINITY;
                bv = v[0]; bi = id[0];
#pragma unroll
                for (int u = 1; u < 16; ++u)
                    if (v[u] > bv || (v[u] == bv && id[u] < bi)) { bv = v[u]; bi = id[u]; }
            }
        }
    }
}

// ---------------- sparse W construction ----------------
__global__ __launch_bounds__(256) void count_indeg(const int* __restrict__ idx, int* __restrict__ cnt) {
    int e = blockIdx.x * 256 + threadIdx.x;
    if (e < NEDGE) atomicAdd(&cnt[idx[e]], 1);
}

// exclusive scan of 4096 counts -> ptr[4097]; zeroes cnt after reading.
__global__ __launch_bounds__(256) void scan_kernel(int* __restrict__ cnt, int* __restrict__ ptr) {
    __shared__ int tmp[256];
    int t = threadIdx.x;
    int base = t * 16;
    int local[16]; int s = 0;
#pragma unroll
    for (int u = 0; u < 16; ++u) { local[u] = s; s += cnt[base + u]; }
#pragma unroll
    for (int u = 0; u < 16; ++u) cnt[base + u] = 0;
    tmp[t] = s;
    __syncthreads();
    for (int off = 1; off < 256; off <<= 1) {
        int v = (t >= off) ? tmp[t - off] : 0;
        __syncthreads();
        tmp[t] += v;
        __syncthreads();
    }
    int prefix = (t > 0) ? tmp[t - 1] : 0;
#pragma unroll
    for (int u = 0; u < 16; ++u) ptr[base + u] = prefix + local[u];
    if (t == 255) ptr[NN_NODES] = prefix + s;
}

__global__ __launch_bounds__(256) void fill_rev(const int* __restrict__ idx, const float* __restrict__ vals,
                                                const int* __restrict__ ptr, int* __restrict__ fcnt,
                                                int* __restrict__ rrow, int* __restrict__ rsrc,
                                                float* __restrict__ rval) {
    int e = blockIdx.x * 256 + threadIdx.x;
    if (e >= NEDGE) return;
    int i = e / KTOP;
    int j = idx[e];
    int p = ptr[j] + atomicAdd(&fcnt[j], 1);
    rrow[p] = j; rsrc[p] = i; rval[p] = vals[e];
}

// fused fwd+rev edge weights (grid covers 2*NEDGE)
__global__ __launch_bounds__(256) void wedges_kernel(const int* __restrict__ idx, const float* __restrict__ vals,
                                                     const int* __restrict__ rrow, const int* __restrict__ rsrc,
                                                     const float* __restrict__ rval,
                                                     float* __restrict__ wfwd, float* __restrict__ wrev) {
    int e = blockIdx.x * 256 + threadIdx.x;
    if (e < NEDGE) {
        int i = e / KTOP;
        int j = idx[e];
        float a = vals[e];
        float c = 1.0f;
        const int* lj = &idx[j * KTOP];
#pragma unroll
        for (int k = 0; k < KTOP; ++k)
            if (lj[k] == i) { a += vals[j * KTOP + k]; c = 2.0f; }
        float w = a / c;
        wfwd[e] = w > 0.f ? w : 0.f;
    } else if (e < 2 * NEDGE) {
        int e2 = e - NEDGE;
        int i = rrow[e2], s = rsrc[e2];
        const int* li = &idx[i * KTOP];
        bool dup = false;
#pragma unroll
        for (int k = 0; k < KTOP; ++k)
            if (li[k] == s) dup = true;
        wrev[e2] = dup ? 0.f : fmaxf(rval[e2], 0.f);
    }
}

// out[i,:] = act(sum_j W[i,j]*X[j,:] + bias)
__global__ __launch_bounds__(256) void spmm_kernel(float* __restrict__ out, const float* __restrict__ X,
                                                   const int* __restrict__ idx, const float* __restrict__ wfwd,
                                                   const int* __restrict__ ptr, const int* __restrict__ rsrc,
                                                   const float* __restrict__ wrev,
                                                   const float* __restrict__ bias, int act) {
    int i = blockIdx.x, c = threadIdx.x;
    float acc = 0.f;
#pragma unroll
    for (int k = 0; k < KTOP; ++k) {
        int j = idx[i * KTOP + k];
        float w = wfwd[i * KTOP + k];
        acc += w * X[(size_t)j * D_H + c];
    }
    int p1 = ptr[i + 1];
    for (int p = ptr[i]; p < p1; ++p) {
        float w = wrev[p];
        if (w != 0.f) acc += w * X[(size_t)rsrc[p] * D_H + c];
    }
    acc += bias[c];
    if (act == 1) acc = fmaxf(acc, 0.f);
    else acc = acc > 0.f ? acc : expm1f(acc);
    out[(size_t)i * D_H + c] = acc;
}

// fused pf/pb over fwd+rev lists; prob = exp(5 s)/zrow
__global__ __launch_bounds__(256) void pfpb_edges(const float* __restrict__ S,
                                                  const int* __restrict__ idx,
                                                  const float* __restrict__ wfwd,
                                                  const int* __restrict__ rrow,
                                                  const int* __restrict__ rsrc,
                                                  const float* __restrict__ wrev,
                                                  const float* __restrict__ zrow,
                                                  float* __restrict__ pf, float* __restrict__ pb) {
    int e = blockIdx.x * 256 + threadIdx.x;
    if (e >= 2 * NEDGE) return;
    int i, j;
    float wv;
    if (e < NEDGE) { i = e / KTOP; j = idx[e]; wv = wfwd[e]; }
    else { int e2 = e - NEDGE; i = rrow[e2]; j = rsrc[e2]; wv = wrev[e2]; }
    if (wv == 0.f) return;
    float sf = S[(size_t)i * NN_NODES + j];
    float sbk = S[(size_t)j * NN_NODES + i];
    float pfv = expf(sf * INV_TEMP) / zrow[i] * wv;
    float pbv = expf(sbk * INV_TEMP) / zrow[j] * wv;
    atomicAdd(&pf[i], pfv);
    atomicAdd(&pb[i], pbv);
}

__global__ __launch_bounds__(256) void loss_kernel(const float* __restrict__ S,
                                                   const float* __restrict__ zrow,
                                                   const float* __restrict__ pf,
                                                   const float* __restrict__ pb,
                                                   float* __restrict__ out) {
    __shared__ float sb[4];
    int t = threadIdx.x;
    float s = 0.f;
    for (int i = t; i < NN_NODES; i += 256) {
        float p = expf(INV_TEMP * S[(size_t)i * NN_NODES + i]) / zrow[i];
        s += -logf(fmaxf(p, EPSV));
        s += 0.5f * (-logf(fmaxf(pf[i], EPSV)) - logf(fmaxf(pb[i], EPSV)));
    }
    float tot = block_reduce_sum(s, sb);
    if (t == 0) out[0] = tot / (float)NN_NODES;
}

// ---------------- launch ----------------
extern "C" void kernel_launch(void* const* d_in, const int* in_sizes, int n_in,
                              void* d_out, int out_size, void* d_ws, size_t ws_size,
                              hipStream_t stream) {
    (void)n_in; (void)out_size; (void)ws_size;
    const float* x = (const float*)d_in[0];
    const int* esrc = (const int*)d_in[1];
    const int* edst = (const int*)d_in[2];
    const float* p_feat = (const float*)d_in[3];
    const float* p_shared = (const float*)d_in[4];
    const float* p_balance = (const float*)d_in[5];
    const float* W1 = (const float*)d_in[6];
    const float* b1 = (const float*)d_in[7];
    const float* W2 = (const float*)d_in[8];
    const float* b2 = (const float*)d_in[9];
    const int E = in_sizes[1];

    float* ws = (float*)d_ws;
    size_t off = 0;
    float* SIM = ws + off; off += (size_t)NN_NODES * NN_NODES;
    float* X1  = ws + off; off += (size_t)NN_NODES * D_IN;
    float* AGG = ws + off; off += (size_t)NN_NODES * D_IN;
    float* T1  = ws + off; off += (size_t)NN_NODES * D_H;
    float* H1  = ws + off; off += (size_t)NN_NODES * D_H;
    float* T2  = ws + off; off += (size_t)NN_NODES * D_H;
    float* Z1  = ws + off; off += (size_t)NN_NODES * D_H;
    float* G1  = ws + off; off += (size_t)NN_NODES * D_H;
    float* Z2  = ws + off; off += (size_t)NN_NODES * D_H;
    float* DINV = ws + off; off += NN_NODES;
    float* VALS = ws + off; off += (size_t)NEDGE;
    int*   IDX  = (int*)(ws + off); off += (size_t)NEDGE;
    float* WFWD = ws + off; off += (size_t)NEDGE;
    int*   RPTR = (int*)(ws + off); off += NN_NODES + 1;
    int*   FCNT = (int*)(ws + off); off += NN_NODES;
    int*   RROW = (int*)(ws + off); off += (size_t)NEDGE;
    int*   RSRC = (int*)(ws + off); off += (size_t)NEDGE;
    float* RVAL = ws + off; off += (size_t)NEDGE;
    float* WREV = ws + off; off += (size_t)NEDGE;
    float* ZROW = ws + off; off += NN_NODES;   // ZROW,PF,PB contiguous (zeroed together)
    float* PF = ws + off; off += NN_NODES;
    float* PB = ws + off; off += NN_NODES;
    unsigned short* HNbf = (unsigned short*)(ws + off); off += (size_t)NN_NODES * D_H / 2;
    unsigned short* Z1bf = (unsigned short*)(ws + off); off += (size_t)NN_NODES * D_H / 2;
    unsigned short* Z2bf = (unsigned short*)(ws + off); off += (size_t)NN_NODES * D_H / 2;
    int* ECNT = (int*)(ws + off); off += NN_NODES;
    int* EPTR = (int*)(ws + off); off += NN_NODES + 1;
    int* ESRT = (int*)(ws + off); off += (size_t)E;

    const int EB = (NEDGE + 255) / 256;
    const int NB = (NN_NODES + 255) / 256;
    const int EBi = (E + 255) / 256;

    // 1. x1
    x1_kernel<<<(NN_NODES * D_IN + 255) / 256, 256, 0, stream>>>(x, p_feat, p_shared, X1);
    // 2. input-graph CSR + dinv (deg = 1 + indegree)
    zero_i<<<NB, 256, 0, stream>>>(ECNT, NN_NODES);
    ecount_kernel<<<EBi, 256, 0, stream>>>(edst, ECNT, E);
    to_dinv<<<NB, 256, 0, stream>>>(ECNT, DINV);
    scan_kernel<<<1, 256, 0, stream>>>(ECNT, EPTR);  // zeroes ECNT for efill
    efill_kernel<<<EBi, 256, 0, stream>>>(esrc, edst, EPTR, ECNT, ESRT, E);
    // zero ZROW/PF/PB (contiguous)
    zero_f<<<(3 * NN_NODES + 255) / 256, 256, 0, stream>>>(ZROW, 3 * NN_NODES);
    // 3. agg = A_norm @ x1  (gather)
    prop_gather<<<NN_NODES, D_IN, 0, stream>>>(AGG, X1, DINV, EPTR, ESRT, nullptr, D_IN, 0);
    // 4. h, hn (bf16)
    h_hn_kernel<<<NN_NODES, 256, 0, stream>>>(X1, AGG, p_balance, HNbf);
    // 5. sim = hn @ hn^T  (MFMA bf16)
    {
        dim3 g(NN_NODES / 128, NN_NODES / 128);
        gemm_nt_mfma<<<g, 256, 0, stream>>>(HNbf, HNbf, SIM, nullptr);
    }
    // 6. topk (threshold prefilter)
    topk_kernel<<<NN_NODES, 256, 0, stream>>>(SIM, VALS, IDX);
    // 7. sparse W: reverse CSR + fused edge weights
    zero_i<<<NB, 256, 0, stream>>>(FCNT, NN_NODES);
    count_indeg<<<EB, 256, 0, stream>>>(IDX, FCNT);
    scan_kernel<<<1, 256, 0, stream>>>(FCNT, RPTR);  // zeroes FCNT for fill_rev
    fill_rev<<<EB, 256, 0, stream>>>(IDX, VALS, RPTR, FCNT, RROW, RSRC, RVAL);
    wedges_kernel<<<2 * EB, 256, 0, stream>>>(IDX, VALS, RROW, RSRC, RVAL, WFWD, WREV);
    // 8. t1 = x1 @ W1
    {
        dim3 g(D_H / BN, NN_NODES / BM);
        gemm_nn_kernel<<<g, 256, 0, stream>>>(X1, W1, T1, NN_NODES, D_H, D_IN, nullptr, 0);
    }
    // 9. h1 = relu(prop(t1) + b1)
    prop_gather<<<NN_NODES, D_H, 0, stream>>>(H1, T1, DINV, EPTR, ESRT, b1, D_H, 1);
    // 10. z1 = elu(prop(h1@W2) + b2)
    {
        dim3 g(D_H / BN, NN_NODES / BM);
        gemm_nn_kernel<<<g, 256, 0, stream>>>(H1, W2, T2, NN_NODES, D_H, D_H, nullptr, 0);
    }
    prop_gather<<<NN_NODES, D_H, 0, stream>>>(Z1, T2, DINV, EPTR, ESRT, b2, D_H, 2);
    // 11. g1 = relu(W @ t1 + b1)   [sparse]
    spmm_kernel<<<NN_NODES, 256, 0, stream>>>(G1, T1, IDX, WFWD, RPTR, RSRC, WREV, b1, 1);
    // 12. g2 = g1 @ W2 (into T2)
    {
        dim3 g(D_H / BN, NN_NODES / BM);
        gemm_nn_kernel<<<g, 256, 0, stream>>>(G1, W2, T2, NN_NODES, D_H, D_H, nullptr, 0);
    }
    // 13. z2 = elu(W @ g2 + b2)   [sparse]
    spmm_kernel<<<NN_NODES, 256, 0, stream>>>(Z2, T2, IDX, WFWD, RPTR, RSRC, WREV, b2, 2);
    // 14. normalize z1, z2 -> bf16 (single launch)
    rownorm2_kernel<<<2 * NN_NODES, 256, 0, stream>>>(Z1, Z1bf, Z2, Z2bf);
    // 15. S = z1n @ z2n^T (MFMA bf16) with fused exp row-sum -> ZROW
    {
        dim3 g(NN_NODES / 128, NN_NODES / 128);
        gemm_nt_mfma<<<g, 256, 0, stream>>>(Z1bf, Z2bf, SIM, ZROW);
    }
    // 16. pf / pb (fused fwd+rev)
    pfpb_edges<<<2 * EB, 256, 0, stream>>>(SIM, IDX, WFWD, RROW, RSRC, WREV, ZROW, PF, PB);
    // 17. loss
    loss_kernel<<<1, 256, 0, stream>>>(SIM, ZROW, PF, PB, (float*)d_out);
}

// Round 12
// 432.857 us; speedup vs baseline: 1.3357x; 1.1023x over previous
//
#include <hip/hip_runtime.h>
#include <math.h>

#define NN_NODES 4096
#define D_IN 128
#define D_H 256
#define KTOP 17
#define NEDGE (NN_NODES * KTOP)
#define INV_TEMP 5.0f
#define EPSV 1e-8f
#define CCAP 1024

typedef __bf16 bf16x8 __attribute__((ext_vector_type(8)));
typedef float f32x4 __attribute__((ext_vector_type(4)));

// ---------------- helpers ----------------
__device__ __forceinline__ float block_reduce_sum(float v, float* sb) {
#pragma unroll
    for (int o = 32; o > 0; o >>= 1) v += __shfl_down(v, o, 64);
    int wid = threadIdx.x >> 6;
    __syncthreads();
    if ((threadIdx.x & 63) == 0) sb[wid] = v;
    __syncthreads();
    return sb[0] + sb[1] + sb[2] + sb[3];
}

// fp32 -> bf16 (RNE)
__device__ __forceinline__ unsigned short f2bf(float x) {
    unsigned u = __float_as_uint(x);
    unsigned r = u + 0x7fff + ((u >> 16) & 1);
    return (unsigned short)(r >> 16);
}

// ---------------- elementwise / setup ----------------
__global__ __launch_bounds__(256) void zero_f(float* p, int n) {
    int i = blockIdx.x * 256 + threadIdx.x;
    if (i < n) p[i] = 0.f;
}

__global__ __launch_bounds__(256) void zero_i(int* p, int n) {
    int i = blockIdx.x * 256 + threadIdx.x;
    if (i < n) p[i] = 0;
}

__global__ __launch_bounds__(256) void x1_kernel(const float* __restrict__ x,
                                                 const float* __restrict__ p_feat,
                                                 const float* __restrict__ p_shared,
                                                 float* __restrict__ x1) {
    int i = blockIdx.x * 256 + threadIdx.x;
    if (i >= NN_NODES * D_IN) return;
    int c = i & (D_IN - 1);
    float v = x[i] * p_feat[c];
    v = fmaxf(v, 0.0f) * p_shared[c];
    x1[i] = v;
}

// dinv[i] = rsqrt(1 + indegree[i])
__global__ __launch_bounds__(256) void to_dinv(const int* __restrict__ cnt, float* __restrict__ dinv) {
    int i = blockIdx.x * 256 + threadIdx.x;
    if (i < NN_NODES) dinv[i] = rsqrtf(1.0f + (float)cnt[i]);
}

// ---------------- input-graph CSR (keyed by dst) ----------------
__global__ __launch_bounds__(256) void ecount_kernel(const int* __restrict__ dst, int* __restrict__ cnt, int E) {
    int e = blockIdx.x * 256 + threadIdx.x;
    if (e < E) atomicAdd(&cnt[dst[e]], 1);
}

__global__ __launch_bounds__(256) void efill_kernel(const int* __restrict__ src, const int* __restrict__ dst,
                                                    const int* __restrict__ ptr, int* __restrict__ cnt,
                                                    int* __restrict__ esrt, int E) {
    int e = blockIdx.x * 256 + threadIdx.x;
    if (e >= E) return;
    int d = dst[e];
    int p = ptr[d] + atomicAdd(&cnt[d], 1);
    esrt[p] = src[e];
}

// out[n][c] = act( dinv[n]^2*h[n][c] + sum_{edges s->n} dinv[s]*dinv[n]*h[s][c] + bias[c] )
__global__ void prop_gather(float* __restrict__ out, const float* __restrict__ h,
                            const float* __restrict__ dinv, const int* __restrict__ eptr,
                            const int* __restrict__ esrt, const float* __restrict__ bias,
                            int C, int act) {
    int n = blockIdx.x, t = threadIdx.x;
    float dn = dinv[n];
    float acc = dn * dn * h[(size_t)n * C + t];
    int p1 = eptr[n + 1];
    for (int p = eptr[n]; p < p1; ++p) {
        int s = esrt[p];
        acc += dinv[s] * dn * h[(size_t)s * C + t];
    }
    if (bias) acc += bias[t];
    if (act == 1) acc = fmaxf(acc, 0.f);
    else if (act == 2) acc = acc > 0.f ? acc : expm1f(acc);
    out[(size_t)n * C + t] = acc;
}

// h = concat(x1, agg)*p_balance; hn = h/(||h||+eps) -> bf16
__global__ __launch_bounds__(256) void h_hn_kernel(const float* __restrict__ x1,
                                                   const float* __restrict__ agg,
                                                   const float* __restrict__ p_balance,
                                                   unsigned short* __restrict__ hn_bf) {
    __shared__ float sb[4];
    int n = blockIdx.x, t = threadIdx.x;
    float v;
    if (t < D_IN) v = x1[(size_t)n * D_IN + t] * p_balance[t];
    else v = agg[(size_t)n * D_IN + (t - D_IN)] * p_balance[t];
    float ss = block_reduce_sum(v * v, sb);
    float inv = 1.0f / (sqrtf(ss) + EPSV);
    hn_bf[(size_t)n * D_H + t] = f2bf(v * inv);
}

// row normalize two Z buffers -> bf16 in one launch (grid 2*NN_NODES)
__global__ __launch_bounds__(256) void rownorm2_kernel(const float* __restrict__ Z1,
                                                       unsigned short* __restrict__ z1bf,
                                                       const float* __restrict__ Z2,
                                                       unsigned short* __restrict__ z2bf) {
    __shared__ float sb[4];
    int b = blockIdx.x, t = threadIdx.x;
    const float* Z = (b < NN_NODES) ? Z1 : Z2;
    unsigned short* zbf = (b < NN_NODES) ? z1bf : z2bf;
    int n = (b < NN_NODES) ? b : b - NN_NODES;
    float v = Z[(size_t)n * D_H + t];
    float ss = block_reduce_sum(v * v, sb);
    float inv = 1.0f / (sqrtf(ss) + EPSV);
    zbf[(size_t)n * D_H + t] = f2bf(v * inv);
}

// ---------------- fp32 GEMM (small NN cases) ----------------
#define BM 64
#define BN 64
#define BK 16

__global__ __launch_bounds__(256) void gemm_nn_kernel(const float* __restrict__ A,
                                                      const float* __restrict__ B,
                                                      float* __restrict__ C, int M, int Nn,
                                                      int Kk, const float* __restrict__ bias,
                                                      int ep) {
    __shared__ float As[BK][BM + 4];
    __shared__ float Bs[BK][BN + 4];
    const int tid = threadIdx.x;
    const int tx = tid & 15, ty = tid >> 4;
    const int m0 = blockIdx.y * BM, n0 = blockIdx.x * BN;
    const int arow = tid >> 2, acol = (tid & 3) << 2;
    const int brow = tid >> 4, bcol = (tid & 15) << 2;
    float acc[4][4] = {{0.f}};

    for (int k0 = 0; k0 < Kk; k0 += BK) {
        float4 av = *(const float4*)&A[(size_t)(m0 + arow) * Kk + k0 + acol];
        float4 bv = *(const float4*)&B[(size_t)(k0 + brow) * Nn + n0 + bcol];
        As[acol + 0][arow] = av.x;
        As[acol + 1][arow] = av.y;
        As[acol + 2][arow] = av.z;
        As[acol + 3][arow] = av.w;
        *(float4*)&Bs[brow][bcol] = bv;
        __syncthreads();
#pragma unroll
        for (int k = 0; k < BK; ++k) {
            float4 a = *(const float4*)&As[k][ty << 2];
            float4 b = *(const float4*)&Bs[k][tx << 2];
            acc[0][0] += a.x * b.x; acc[0][1] += a.x * b.y; acc[0][2] += a.x * b.z; acc[0][3] += a.x * b.w;
            acc[1][0] += a.y * b.x; acc[1][1] += a.y * b.y; acc[1][2] += a.y * b.z; acc[1][3] += a.y * b.w;
            acc[2][0] += a.z * b.x; acc[2][1] += a.z * b.y; acc[2][2] += a.z * b.z; acc[2][3] += a.z * b.w;
            acc[3][0] += a.w * b.x; acc[3][1] += a.w * b.y; acc[3][2] += a.w * b.z; acc[3][3] += a.w * b.w;
        }
        __syncthreads();
    }
    float bb[4] = {0.f, 0.f, 0.f, 0.f};
    if (ep) {
#pragma unroll
        for (int j = 0; j < 4; ++j) bb[j] = bias[n0 + (tx << 2) + j];
    }
#pragma unroll
    for (int i = 0; i < 4; ++i) {
        int m = m0 + (ty << 2) + i;
        float r[4];
#pragma unroll
        for (int j = 0; j < 4; ++j) {
            float v = acc[i][j] + bb[j];
            if (ep == 1) v = fmaxf(v, 0.0f);
            else if (ep == 2) v = v > 0.0f ? v : expm1f(v);
            r[j] = v;
        }
        *(float4*)&C[(size_t)m * Nn + n0 + (tx << 2)] = *(float4*)r;
    }
}

// ---------------- MFMA NT GEMM: C[4096,4096] = X @ Y^T, K=256, single bf16 ----------------
__global__ __launch_bounds__(256) void gemm_nt_mfma(const unsigned short* __restrict__ Abf,
                                                    const unsigned short* __restrict__ Bbf,
                                                    float* __restrict__ C,
                                                    float* __restrict__ zrow) {
    __shared__ unsigned short lds[2 * 16 * 512];  // 32 KB
    const int tid = threadIdx.x;
    const int w = tid >> 6, lane = tid & 63;
    const int m0 = blockIdx.y * 128, n0 = blockIdx.x * 128;
    const int wmt = (w >> 1) * 4;
    const int wnt = (w & 1) * 4;

    f32x4 acc[4][4];
#pragma unroll
    for (int i = 0; i < 4; ++i)
#pragma unroll
        for (int j = 0; j < 4; ++j) acc[i][j] = (f32x4)(0.f);

    unsigned short* Ah = lds;
    unsigned short* Bh = lds + 8192;

    const unsigned short* srcs[2] = {Abf, Bbf};
    unsigned short* dsts[2] = {Ah, Bh};

    const int lrow = lane & 15, lquad = lane >> 4;

    for (int k0 = 0; k0 < 256; k0 += 64) {
#pragma unroll
        for (int arr = 0; arr < 2; ++arr) {
            const unsigned short* src = srcs[arr];
            unsigned short* dst = dsts[arr];
            const int base0 = (arr == 0) ? m0 : n0;
#pragma unroll
            for (int ti = 0; ti < 4; ++ti) {
                int t = w + ti * 4;
                int row = base0 + (t & 7) * 16 + lrow;
                int kk = k0 + (t >> 3) * 32 + lquad * 8;
                uint4 v = *(const uint4*)&src[(size_t)row * 256 + kk];
                *(uint4*)&dst[t * 512 + lane * 8] = v;
            }
        }
        __syncthreads();
#pragma unroll
        for (int ksub = 0; ksub < 2; ++ksub) {
            bf16x8 a[4], b[4];
#pragma unroll
            for (int i = 0; i < 4; ++i) {
                a[i] = __builtin_bit_cast(bf16x8, *(const uint4*)&Ah[(ksub * 8 + wmt + i) * 512 + lane * 8]);
                b[i] = __builtin_bit_cast(bf16x8, *(const uint4*)&Bh[(ksub * 8 + wnt + i) * 512 + lane * 8]);
            }
#pragma unroll
            for (int i = 0; i < 4; ++i)
#pragma unroll
                for (int j = 0; j < 4; ++j)
                    acc[i][j] = __builtin_amdgcn_mfma_f32_16x16x32_bf16(a[i], b[j], acc[i][j], 0, 0, 0);
        }
        __syncthreads();
    }
    const int col = lane & 15, rq = (lane >> 4) * 4;
#pragma unroll
    for (int i = 0; i < 4; ++i) {
        int rb = m0 + (wmt + i) * 16 + rq;
#pragma unroll
        for (int j = 0; j < 4; ++j) {
            int cb = n0 + (wnt + j) * 16 + col;
#pragma unroll
            for (int r = 0; r < 4; ++r)
                C[(size_t)(rb + r) * NN_NODES + cb] = acc[i][j][r];
        }
    }
    if (zrow) {
#pragma unroll
        for (int i = 0; i < 4; ++i) {
            int rb = m0 + (wmt + i) * 16 + rq;
#pragma unroll
            for (int r = 0; r < 4; ++r) {
                float s = 0.f;
#pragma unroll
                for (int j = 0; j < 4; ++j) s += __expf(INV_TEMP * acc[i][j][r]);
#pragma unroll
                for (int o = 1; o < 16; o <<= 1) s += __shfl_xor(s, o, 64);
                if ((lane & 15) == 0) atomicAdd(&zrow[rb + r], s);
            }
        }
    }
}

// ---------------- top-k: threshold prefilter + rank-based selection ----------------
// T = 17th-largest of 64 group maxima (groups of 4 threads) => >=17 elements >= T
// => candidates {x >= T} contain exact top-17. All waves compute T redundantly
// (63-step shfl_xor rank loop, no serial wave-0 phase). Final selection: each
// thread ranks its candidate against the LDS list (broadcast reads) and writes
// vals[rank] directly. Exact JAX order (value desc, index asc; indices unique).
__global__ __launch_bounds__(256) void topk_kernel(const float* __restrict__ S,
                                                   float* __restrict__ vals,
                                                   int* __restrict__ idxo) {
    __shared__ float sm[256];
    __shared__ int ccnt;
    __shared__ float cv[CCAP];
    __shared__ int ci[CCAP];
    __shared__ float wvs[8];
    __shared__ int wis[8];
    const int i = blockIdx.x, t = threadIdx.x;
    const int lane = t & 63, wid = t >> 6;
    const float* row = &S[(size_t)i * NN_NODES];
    float v[16];
    int id[16];
#pragma unroll
    for (int u = 0; u < 4; ++u) {
        int base = u * 1024 + t * 4;
        float4 f = *(const float4*)&row[base];
        v[u * 4 + 0] = f.x; id[u * 4 + 0] = base + 0;
        v[u * 4 + 1] = f.y; id[u * 4 + 1] = base + 1;
        v[u * 4 + 2] = f.z; id[u * 4 + 2] = base + 2;
        v[u * 4 + 3] = f.w; id[u * 4 + 3] = base + 3;
    }
    float m = v[0];
#pragma unroll
    for (int u = 1; u < 16; ++u) m = fmaxf(m, v[u]);
    sm[t] = m;
    if (t == 0) ccnt = 0;
    __syncthreads();

    // every wave: T = 17th-largest of 64 group maxima (rank via shfl loop)
    float g = fmaxf(fmaxf(sm[lane * 4 + 0], sm[lane * 4 + 1]),
                    fmaxf(sm[lane * 4 + 2], sm[lane * 4 + 3]));
    int rank = 0;
#pragma unroll
    for (int o = 1; o < 64; ++o) {
        float ov = __shfl_xor(g, o, 64);
        int ol = lane ^ o;
        if (ov > g || (ov == g && ol < lane)) rank++;
    }
    unsigned long long ball = __ballot(rank == 16);
    int tl = __ffsll((long long)ball) - 1;
    const float T = __shfl(g, tl, 64);

    // emit candidates >= T
#pragma unroll
    for (int u = 0; u < 16; ++u) {
        if (v[u] >= T) {
            int p = atomicAdd(&ccnt, 1);
            if (p < CCAP) { cv[p] = v[u]; ci[p] = id[u]; }
        }
    }
    __syncthreads();
    const int cnt = ccnt;

    if (cnt <= CCAP) {
        // rank-based exact selection: each thread handles candidates t, t+256, ...
        for (int p = t; p < cnt; p += 256) {
            float mv = cv[p];
            int mi = ci[p];
            int r = 0;
            for (int q = 0; q < cnt; ++q) {
                float qv = cv[q];
                int qi = ci[q];
                if (qv > mv || (qv == mv && qi < mi)) r++;
            }
            if (r < KTOP) {
                vals[i * KTOP + r] = isnan(mv) ? 0.f : mv;
                idxo[i * KTOP + r] = mi;
            }
        }
    } else {
        // fallback: full block-wide cached-candidate extraction (registers intact)
        float bv = v[0];
        int bi = id[0];
#pragma unroll
        for (int u = 1; u < 16; ++u)
            if (v[u] > bv || (v[u] == bv && id[u] < bi)) { bv = v[u]; bi = id[u]; }
        for (int k = 0; k < KTOP; ++k) {
            float mv = bv;
            int mi = bi;
#pragma unroll
            for (int o = 1; o < 64; o <<= 1) {
                float ov = __shfl_xor(mv, o, 64);
                int oi = __shfl_xor(mi, o, 64);
                if (ov > mv || (ov == mv && oi < mi)) { mv = ov; mi = oi; }
            }
            int slot = ((k & 1) << 2) + wid;
            if (lane == 0) { wvs[slot] = mv; wis[slot] = mi; }
            __syncthreads();
            int b0 = (k & 1) << 2;
            mv = wvs[b0]; mi = wis[b0];
#pragma unroll
            for (int ww = 1; ww < 4; ++ww) {
                float ov = wvs[b0 + ww];
                int oi = wis[b0 + ww];
                if (ov > mv || (ov == mv && oi < mi)) { mv = ov; mi = oi; }
            }
            if (t == 0) {
                vals[i * KTOP + k] = isnan(mv) ? 0.f : mv;
                idxo[i * KTOP + k] = mi;
            }
            if (bi == mi) {
#pragma unroll
                for (int u = 0; u < 16; ++u)
                    if (id[u] == mi) v[u] = -INFINITY;
                bv = v[0]; bi = id[0];
#pragma unroll
                for (int u = 1; u < 16; ++u)
                    if (v[u] > bv || (v[u] == bv && id[u] < bi)) { bv = v[u]; bi = id[u]; }
            }
        }
    }
}

// ---------------- sparse W construction ----------------
__global__ __launch_bounds__(256) void count_indeg(const int* __restrict__ idx, int* __restrict__ cnt) {
    int e = blockIdx.x * 256 + threadIdx.x;
    if (e < NEDGE) atomicAdd(&cnt[idx[e]], 1);
}

// exclusive scan of 4096 counts -> ptr[4097]; zeroes cnt after reading.
__global__ __launch_bounds__(256) void scan_kernel(int* __restrict__ cnt, int* __restrict__ ptr) {
    __shared__ int tmp[256];
    int t = threadIdx.x;
    int base = t * 16;
    int local[16]; int s = 0;
#pragma unroll
    for (int u = 0; u < 16; ++u) { local[u] = s; s += cnt[base + u]; }
#pragma unroll
    for (int u = 0; u < 16; ++u) cnt[base + u] = 0;
    tmp[t] = s;
    __syncthreads();
    for (int off = 1; off < 256; off <<= 1) {
        int v = (t >= off) ? tmp[t - off] : 0;
        __syncthreads();
        tmp[t] += v;
        __syncthreads();
    }
    int prefix = (t > 0) ? tmp[t - 1] : 0;
#pragma unroll
    for (int u = 0; u < 16; ++u) ptr[base + u] = prefix + local[u];
    if (t == 255) ptr[NN_NODES] = prefix + s;
}

__global__ __launch_bounds__(256) void fill_rev(const int* __restrict__ idx, const float* __restrict__ vals,
                                                const int* __restrict__ ptr, int* __restrict__ fcnt,
                                                int* __restrict__ rrow, int* __restrict__ rsrc,
                                                float* __restrict__ rval) {
    int e = blockIdx.x * 256 + threadIdx.x;
    if (e >= NEDGE) return;
    int i = e / KTOP;
    int j = idx[e];
    int p = ptr[j] + atomicAdd(&fcnt[j], 1);
    rrow[p] = j; rsrc[p] = i; rval[p] = vals[e];
}

// fused fwd+rev edge weights (grid covers 2*NEDGE)
__global__ __launch_bounds__(256) void wedges_kernel(const int* __restrict__ idx, const float* __restrict__ vals,
                                                     const int* __restrict__ rrow, const int* __restrict__ rsrc,
                                                     const float* __restrict__ rval,
                                                     float* __restrict__ wfwd, float* __restrict__ wrev) {
    int e = blockIdx.x * 256 + threadIdx.x;
    if (e < NEDGE) {
        int i = e / KTOP;
        int j = idx[e];
        float a = vals[e];
        float c = 1.0f;
        const int* lj = &idx[j * KTOP];
#pragma unroll
        for (int k = 0; k < KTOP; ++k)
            if (lj[k] == i) { a += vals[j * KTOP + k]; c = 2.0f; }
        float w = a / c;
        wfwd[e] = w > 0.f ? w : 0.f;
    } else if (e < 2 * NEDGE) {
        int e2 = e - NEDGE;
        int i = rrow[e2], s = rsrc[e2];
        const int* li = &idx[i * KTOP];
        bool dup = false;
#pragma unroll
        for (int k = 0; k < KTOP; ++k)
            if (li[k] == s) dup = true;
        wrev[e2] = dup ? 0.f : fmaxf(rval[e2], 0.f);
    }
}

// out[i,:] = act(sum_j W[i,j]*X[j,:] + bias)
__global__ __launch_bounds__(256) void spmm_kernel(float* __restrict__ out, const float* __restrict__ X,
                                                   const int* __restrict__ idx, const float* __restrict__ wfwd,
                                                   const int* __restrict__ ptr, const int* __restrict__ rsrc,
                                                   const float* __restrict__ wrev,
                                                   const float* __restrict__ bias, int act) {
    int i = blockIdx.x, c = threadIdx.x;
    float acc = 0.f;
#pragma unroll
    for (int k = 0; k < KTOP; ++k) {
        int j = idx[i * KTOP + k];
        float w = wfwd[i * KTOP + k];
        acc += w * X[(size_t)j * D_H + c];
    }
    int p1 = ptr[i + 1];
    for (int p = ptr[i]; p < p1; ++p) {
        float w = wrev[p];
        if (w != 0.f) acc += w * X[(size_t)rsrc[p] * D_H + c];
    }
    acc += bias[c];
    if (act == 1) acc = fmaxf(acc, 0.f);
    else acc = acc > 0.f ? acc : expm1f(acc);
    out[(size_t)i * D_H + c] = acc;
}

// fused pf/pb over fwd+rev lists; prob = exp(5 s)/zrow
__global__ __launch_bounds__(256) void pfpb_edges(const float* __restrict__ S,
                                                  const int* __restrict__ idx,
                                                  const float* __restrict__ wfwd,
                                                  const int* __restrict__ rrow,
                                                  const int* __restrict__ rsrc,
                                                  const float* __restrict__ wrev,
                                                  const float* __restrict__ zrow,
                                                  float* __restrict__ pf, float* __restrict__ pb) {
    int e = blockIdx.x * 256 + threadIdx.x;
    if (e >= 2 * NEDGE) return;
    int i, j;
    float wv;
    if (e < NEDGE) { i = e / KTOP; j = idx[e]; wv = wfwd[e]; }
    else { int e2 = e - NEDGE; i = rrow[e2]; j = rsrc[e2]; wv = wrev[e2]; }
    if (wv == 0.f) return;
    float sf = S[(size_t)i * NN_NODES + j];
    float sbk = S[(size_t)j * NN_NODES + i];
    float pfv = expf(sf * INV_TEMP) / zrow[i] * wv;
    float pbv = expf(sbk * INV_TEMP) / zrow[j] * wv;
    atomicAdd(&pf[i], pfv);
    atomicAdd(&pb[i], pbv);
}

__global__ __launch_bounds__(256) void loss_kernel(const float* __restrict__ S,
                                                   const float* __restrict__ zrow,
                                                   const float* __restrict__ pf,
                                                   const float* __restrict__ pb,
                                                   float* __restrict__ out) {
    __shared__ float sb[4];
    int t = threadIdx.x;
    float s = 0.f;
    for (int i = t; i < NN_NODES; i += 256) {
        float p = expf(INV_TEMP * S[(size_t)i * NN_NODES + i]) / zrow[i];
        s += -logf(fmaxf(p, EPSV));
        s += 0.5f * (-logf(fmaxf(pf[i], EPSV)) - logf(fmaxf(pb[i], EPSV)));
    }
    float tot = block_reduce_sum(s, sb);
    if (t == 0) out[0] = tot / (float)NN_NODES;
}

// ---------------- launch ----------------
extern "C" void kernel_launch(void* const* d_in, const int* in_sizes, int n_in,
                              void* d_out, int out_size, void* d_ws, size_t ws_size,
                              hipStream_t stream) {
    (void)n_in; (void)out_size; (void)ws_size;
    const float* x = (const float*)d_in[0];
    const int* esrc = (const int*)d_in[1];
    const int* edst = (const int*)d_in[2];
    const float* p_feat = (const float*)d_in[3];
    const float* p_shared = (const float*)d_in[4];
    const float* p_balance = (const float*)d_in[5];
    const float* W1 = (const float*)d_in[6];
    const float* b1 = (const float*)d_in[7];
    const float* W2 = (const float*)d_in[8];
    const float* b2 = (const float*)d_in[9];
    const int E = in_sizes[1];

    float* ws = (float*)d_ws;
    size_t off = 0;
    float* SIM = ws + off; off += (size_t)NN_NODES * NN_NODES;
    float* X1  = ws + off; off += (size_t)NN_NODES * D_IN;
    float* AGG = ws + off; off += (size_t)NN_NODES * D_IN;
    float* T1  = ws + off; off += (size_t)NN_NODES * D_H;
    float* H1  = ws + off; off += (size_t)NN_NODES * D_H;
    float* T2  = ws + off; off += (size_t)NN_NODES * D_H;
    float* Z1  = ws + off; off += (size_t)NN_NODES * D_H;
    float* G1  = ws + off; off += (size_t)NN_NODES * D_H;
    float* Z2  = ws + off; off += (size_t)NN_NODES * D_H;
    float* DINV = ws + off; off += NN_NODES;
    float* VALS = ws + off; off += (size_t)NEDGE;
    int*   IDX  = (int*)(ws + off); off += (size_t)NEDGE;
    float* WFWD = ws + off; off += (size_t)NEDGE;
    int*   RPTR = (int*)(ws + off); off += NN_NODES + 1;
    int*   FCNT = (int*)(ws + off); off += NN_NODES;
    int*   RROW = (int*)(ws + off); off += (size_t)NEDGE;
    int*   RSRC = (int*)(ws + off); off += (size_t)NEDGE;
    float* RVAL = ws + off; off += (size_t)NEDGE;
    float* WREV = ws + off; off += (size_t)NEDGE;
    float* ZROW = ws + off; off += NN_NODES;   // ZROW,PF,PB contiguous (zeroed together)
    float* PF = ws + off; off += NN_NODES;
    float* PB = ws + off; off += NN_NODES;
    unsigned short* HNbf = (unsigned short*)(ws + off); off += (size_t)NN_NODES * D_H / 2;
    unsigned short* Z1bf = (unsigned short*)(ws + off); off += (size_t)NN_NODES * D_H / 2;
    unsigned short* Z2bf = (unsigned short*)(ws + off); off += (size_t)NN_NODES * D_H / 2;
    int* ECNT = (int*)(ws + off); off += NN_NODES;
    int* EPTR = (int*)(ws + off); off += NN_NODES + 1;
    int* ESRT = (int*)(ws + off); off += (size_t)E;

    const int EB = (NEDGE + 255) / 256;
    const int NB = (NN_NODES + 255) / 256;
    const int EBi = (E + 255) / 256;

    // 1. x1
    x1_kernel<<<(NN_NODES * D_IN + 255) / 256, 256, 0, stream>>>(x, p_feat, p_shared, X1);
    // 2. input-graph CSR + dinv (deg = 1 + indegree)
    zero_i<<<NB, 256, 0, stream>>>(ECNT, NN_NODES);
    ecount_kernel<<<EBi, 256, 0, stream>>>(edst, ECNT, E);
    to_dinv<<<NB, 256, 0, stream>>>(ECNT, DINV);
    scan_kernel<<<1, 256, 0, stream>>>(ECNT, EPTR);  // zeroes ECNT for efill
    efill_kernel<<<EBi, 256, 0, stream>>>(esrc, edst, EPTR, ECNT, ESRT, E);
    // zero ZROW/PF/PB (contiguous)
    zero_f<<<(3 * NN_NODES + 255) / 256, 256, 0, stream>>>(ZROW, 3 * NN_NODES);
    // 3. agg = A_norm @ x1  (gather)
    prop_gather<<<NN_NODES, D_IN, 0, stream>>>(AGG, X1, DINV, EPTR, ESRT, nullptr, D_IN, 0);
    // 4. h, hn (bf16)
    h_hn_kernel<<<NN_NODES, 256, 0, stream>>>(X1, AGG, p_balance, HNbf);
    // 5. sim = hn @ hn^T  (MFMA bf16)
    {
        dim3 g(NN_NODES / 128, NN_NODES / 128);
        gemm_nt_mfma<<<g, 256, 0, stream>>>(HNbf, HNbf, SIM, nullptr);
    }
    // 6. topk (threshold prefilter + rank selection)
    topk_kernel<<<NN_NODES, 256, 0, stream>>>(SIM, VALS, IDX);
    // 7. sparse W: reverse CSR + fused edge weights
    zero_i<<<NB, 256, 0, stream>>>(FCNT, NN_NODES);
    count_indeg<<<EB, 256, 0, stream>>>(IDX, FCNT);
    scan_kernel<<<1, 256, 0, stream>>>(FCNT, RPTR);  // zeroes FCNT for fill_rev
    fill_rev<<<EB, 256, 0, stream>>>(IDX, VALS, RPTR, FCNT, RROW, RSRC, RVAL);
    wedges_kernel<<<2 * EB, 256, 0, stream>>>(IDX, VALS, RROW, RSRC, RVAL, WFWD, WREV);
    // 8. t1 = x1 @ W1
    {
        dim3 g(D_H / BN, NN_NODES / BM);
        gemm_nn_kernel<<<g, 256, 0, stream>>>(X1, W1, T1, NN_NODES, D_H, D_IN, nullptr, 0);
    }
    // 9. h1 = relu(prop(t1) + b1)
    prop_gather<<<NN_NODES, D_H, 0, stream>>>(H1, T1, DINV, EPTR, ESRT, b1, D_H, 1);
    // 10. z1 = elu(prop(h1@W2) + b2)
    {
        dim3 g(D_H / BN, NN_NODES / BM);
        gemm_nn_kernel<<<g, 256, 0, stream>>>(H1, W2, T2, NN_NODES, D_H, D_H, nullptr, 0);
    }
    prop_gather<<<NN_NODES, D_H, 0, stream>>>(Z1, T2, DINV, EPTR, ESRT, b2, D_H, 2);
    // 11. g1 = relu(W @ t1 + b1)   [sparse]
    spmm_kernel<<<NN_NODES, 256, 0, stream>>>(G1, T1, IDX, WFWD, RPTR, RSRC, WREV, b1, 1);
    // 12. g2 = g1 @ W2 (into T2)
    {
        dim3 g(D_H / BN, NN_NODES / BM);
        gemm_nn_kernel<<<g, 256, 0, stream>>>(G1, W2, T2, NN_NODES, D_H, D_H, nullptr, 0);
    }
    // 13. z2 = elu(W @ g2 + b2)   [sparse]
    spmm_kernel<<<NN_NODES, 256, 0, stream>>>(Z2, T2, IDX, WFWD, RPTR, RSRC, WREV, b2, 2);
    // 14. normalize z1, z2 -> bf16 (single launch)
    rownorm2_kernel<<<2 * NN_NODES, 256, 0, stream>>>(Z1, Z1bf, Z2, Z2bf);
    // 15. S = z1n @ z2n^T (MFMA bf16) with fused exp row-sum -> ZROW
    {
        dim3 g(NN_NODES / 128, NN_NODES / 128);
        gemm_nt_mfma<<<g, 256, 0, stream>>>(Z1bf, Z2bf, SIM, ZROW);
    }
    // 16. pf / pb (fused fwd+rev)
    pfpb_edges<<<2 * EB, 256, 0, stream>>>(SIM, IDX, WFWD, RROW, RSRC, WREV, ZROW, PF, PB);
    // 17. loss
    loss_kernel<<<1, 256, 0, stream>>>(SIM, ZROW, PF, PB, (float*)d_out);
}